// Round 1
// baseline (644.690 us; speedup 1.0000x reference)
//
#include <hip/hip_runtime.h>
#include <stdint.h>

typedef __bf16 bf16x8 __attribute__((ext_vector_type(8)));
typedef float f32x4 __attribute__((ext_vector_type(4)));
typedef unsigned short u16;
typedef u16 u16x8 __attribute__((ext_vector_type(8)));
typedef u16 u16x4 __attribute__((ext_vector_type(4)));
typedef uint32_t u32;

#define DEV __device__ __forceinline__

static constexpr int B_ = 4, S_ = 2048, M_ = 8192, D_ = 1024, H_ = 16, DFF_ = 4096;

DEV u16 f2bf(float f) {
    union { float f; u32 u; } c; c.f = f;
    u32 u = c.u;
    return (u16)((u + 0x7fffu + ((u >> 16) & 1u)) >> 16);
}

DEV void gload16(void* lds, const void* g) {
    __builtin_amdgcn_global_load_lds(
        (const __attribute__((address_space(1))) unsigned int*)g,
        (__attribute__((address_space(3))) unsigned int*)lds, 16, 0, 0);
}

// ---------------- pre-pass kernels ----------------

__global__ __launch_bounds__(256) void k_pack_mask(const int* __restrict__ m,
                                                   u32* __restrict__ bits, int nwords) {
    int w = blockIdx.x * 256 + threadIdx.x;
    if (w >= nwords) return;
    const int4* s = (const int4*)(m + (size_t)w * 32);
    u32 r = 0;
#pragma unroll
    for (int j = 0; j < 8; j++) {
        int4 v = s[j];
        r |= (u32)(v.x != 0) << (j * 4) | (u32)(v.y != 0) << (j * 4 + 1) |
             (u32)(v.z != 0) << (j * 4 + 2) | (u32)(v.w != 0) << (j * 4 + 3);
    }
    bits[w] = r;
}

__global__ __launch_bounds__(256) void k_cast_bf16(const float* __restrict__ s,
                                                   u16* __restrict__ d, int n4) {
    int i = blockIdx.x * 256 + threadIdx.x;
    if (i >= n4) return;
    f32x4 v = ((const f32x4*)s)[i];
    u16x4 o;
    o[0] = f2bf(v[0]); o[1] = f2bf(v[1]); o[2] = f2bf(v[2]); o[3] = f2bf(v[3]);
    ((u16x4*)d)[i] = o;
}

// src [K][N] f32 -> dst [N][K] bf16
__global__ void k_transpose_cast(const float* __restrict__ s, u16* __restrict__ d,
                                 int K, int N) {
    __shared__ float t[32][33];
    int n0 = blockIdx.x * 32, k0 = blockIdx.y * 32;
    int tx = threadIdx.x, ty = threadIdx.y;
#pragma unroll
    for (int i = 0; i < 4; i++)
        t[ty + i * 8][tx] = s[(size_t)(k0 + ty + i * 8) * N + n0 + tx];
    __syncthreads();
#pragma unroll
    for (int i = 0; i < 4; i++)
        d[(size_t)(n0 + ty + i * 8) * K + k0 + tx] = f2bf(t[tx][ty + i * 8]);
}

// ---------------- GEMM: C[M,N] = A[M,K] * Bt[N,K]^T (bf16 in, f32 acc) ----------------
// EPI 0: QKV scatter bf16; 1: f32 store; 2: +bias, relu, bf16; 3: +bias, f32
template <int EPI>
__global__ __launch_bounds__(256) void k_gemm_bt(const u16* __restrict__ A,
                                                 const u16* __restrict__ Bt,
                                                 float* __restrict__ Cf,
                                                 u16* __restrict__ Cb,
                                                 const float* __restrict__ bias,
                                                 int N, int K) {
    __shared__ u16 As[128 * 32];
    __shared__ u16 Bs[128 * 32];
    const int tid = threadIdx.x, lane = tid & 63, wave = tid >> 6;
    const int lr = lane & 15, lg = lane >> 4;
    const size_t row0 = (size_t)blockIdx.y * 128;
    const int col0 = blockIdx.x * 128;
    const int wm = (wave >> 1) * 64, wn = (wave & 1) * 64;
    f32x4 acc[4][4] = {};
    for (int k0 = 0; k0 < K; k0 += 32) {
#pragma unroll
        for (int p = 0; p < 2; p++) {
            int off = p * 4096 + wave * 1024 + lane * 16;
            int r = off >> 6, cb = off & 63;
            gload16((char*)As + p * 4096 + wave * 1024,
                    (const char*)(A + (row0 + r) * K + k0) + cb);
            gload16((char*)Bs + p * 4096 + wave * 1024,
                    (const char*)(Bt + (size_t)(col0 + r) * K + k0) + cb);
        }
        __syncthreads();
        bf16x8 aF[4], bF[4];
#pragma unroll
        for (int m = 0; m < 4; m++)
            aF[m] = *(const bf16x8*)((const char*)As + (wm + m * 16 + lr) * 64 + lg * 16);
#pragma unroll
        for (int n = 0; n < 4; n++)
            bF[n] = *(const bf16x8*)((const char*)Bs + (wn + n * 16 + lr) * 64 + lg * 16);
#pragma unroll
        for (int m = 0; m < 4; m++)
#pragma unroll
            for (int n = 0; n < 4; n++)
                acc[m][n] = __builtin_amdgcn_mfma_f32_16x16x32_bf16(aF[m], bF[n],
                                                                   acc[m][n], 0, 0, 0);
        __syncthreads();
    }
#pragma unroll
    for (int m = 0; m < 4; m++)
#pragma unroll
        for (int n = 0; n < 4; n++)
#pragma unroll
            for (int i = 0; i < 4; i++) {
                int rg = (int)row0 + wm + m * 16 + lg * 4 + i;
                int cg = col0 + wn + n * 16 + lr;
                float v = acc[m][n][i];
                if constexpr (EPI == 0) {
                    int proj = cg >> 10, hh = (cg >> 6) & 15, dk = cg & 63;
                    int b = rg >> 11, s = rg & 2047;
                    size_t idx = ((size_t)(proj * 64 + b * 16 + hh) * 2048 + s) * 64 + dk;
                    Cb[idx] = f2bf(v);
                } else if constexpr (EPI == 1) {
                    Cf[(size_t)rg * N + cg] = v;
                } else if constexpr (EPI == 2) {
                    v += bias[cg];
                    v = v > 0.f ? v : 0.f;
                    Cb[(size_t)rg * N + cg] = f2bf(v);
                } else {
                    Cf[(size_t)rg * N + cg] = v + bias[cg];
                }
            }
}

// ---------------- flash attention ----------------
// qkv layout: [(proj*64 + b*16 + h)][s][64] bf16. out: [b*2048+s][1024] bf16.
__global__ __launch_bounds__(256) void k_attn(const u16* __restrict__ qkv,
                                              const u32* __restrict__ mbits,
                                              u16* __restrict__ outb) {
    __shared__ u16 Kt[64 * 64];
    __shared__ u16 Vt[64 * 64];
    __shared__ u16 Pt[4][32 * 64];
    __shared__ u32 pm[128][2];
    const int tid = threadIdx.x, lane = tid & 63, wave = tid >> 6;
    const int lr = lane & 15, lg = lane >> 4;
    const int bh = blockIdx.y;
    const int b = bh >> 4, h = bh & 15;
    const int qb0 = blockIdx.x * 128;
    const size_t qbase = (size_t)bh * (2048 * 64);
    const size_t kbase = (size_t)(64 + bh) * (2048 * 64);
    const size_t vbase = (size_t)(128 + bh) * (2048 * 64);

    bf16x8 qf[2][2];
    const int q0 = qb0 + wave * 32;
#pragma unroll
    for (int rs = 0; rs < 2; rs++)
#pragma unroll
        for (int kf = 0; kf < 2; kf++)
            qf[rs][kf] = *(const bf16x8*)(qkv + qbase +
                                          (size_t)(q0 + rs * 16 + lr) * 64 + kf * 32 + lg * 8);

    f32x4 o[2][4] = {};
    f32x4 mx[2] = {{-1e30f, -1e30f, -1e30f, -1e30f}, {-1e30f, -1e30f, -1e30f, -1e30f}};
    f32x4 ls[2] = {};
    const int str = tid >> 2, sq = tid & 3;

    for (int kv0 = 0; kv0 < 2048; kv0 += 64) {
        __syncthreads();
        {   // stage K (swizzled rows of 128B)
            const u16* src = qkv + kbase + (size_t)(kv0 + str) * 64 + sq * 16;
            u16x8 v0 = *(const u16x8*)src, v1 = *(const u16x8*)(src + 8);
            int b0 = str * 128 + sq * 32, swz = (str & 7) << 4;
            *(u16x8*)((char*)Kt + ((b0) ^ swz)) = v0;
            *(u16x8*)((char*)Kt + ((b0 + 16) ^ swz)) = v1;
        }
        {   // stage V transposed (Vt[d][kv]), swizzled
            const u16* src = qkv + vbase + (size_t)(kv0 + str) * 64 + sq * 16;
            u16x8 v0 = *(const u16x8*)src, v1 = *(const u16x8*)(src + 8);
#pragma unroll
            for (int e = 0; e < 8; e++) {
                int d0 = sq * 16 + e, d1 = sq * 16 + 8 + e;
                *(u16*)((char*)Vt + ((d0 * 128 + str * 2) ^ ((d0 & 7) << 4))) = v0[e];
                *(u16*)((char*)Vt + ((d1 * 128 + str * 2) ^ ((d1 & 7) << 4))) = v1[e];
            }
        }
        {   // stage mask words for this kv tile
            int ql = tid >> 1, w = tid & 1;
            pm[ql][w] = mbits[(size_t)(b * 2048 + qb0 + ql) * 64 + (kv0 >> 5) + w];
        }
        __syncthreads();

        bf16x8 kfr[4][2];
#pragma unroll
        for (int ks = 0; ks < 4; ks++)
#pragma unroll
            for (int kf = 0; kf < 2; kf++) {
                int rr = ks * 16 + lr;
                kfr[ks][kf] = *(const bf16x8*)((char*)Kt +
                              ((rr * 128 + kf * 64 + lg * 16) ^ ((rr & 7) << 4)));
            }
        f32x4 s[2][4];
#pragma unroll
        for (int rs = 0; rs < 2; rs++)
#pragma unroll
            for (int ks = 0; ks < 4; ks++) {
                f32x4 z = {0.f, 0.f, 0.f, 0.f};
                z = __builtin_amdgcn_mfma_f32_16x16x32_bf16(qf[rs][0], kfr[ks][0], z, 0, 0, 0);
                z = __builtin_amdgcn_mfma_f32_16x16x32_bf16(qf[rs][1], kfr[ks][1], z, 0, 0, 0);
                s[rs][ks] = z;
            }
        // scale + mask
#pragma unroll
        for (int rs = 0; rs < 2; rs++)
#pragma unroll
            for (int ks = 0; ks < 4; ks++)
#pragma unroll
                for (int i = 0; i < 4; i++) {
                    int ql = wave * 32 + rs * 16 + lg * 4 + i;
                    int kvl = ks * 16 + lr;
                    u32 bit = (pm[ql][kvl >> 5] >> (kvl & 31)) & 1u;
                    float val = s[rs][ks][i] * 0.125f;
                    s[rs][ks][i] = bit ? val : -1e9f;
                }
        // online softmax per row-block
#pragma unroll
        for (int rs = 0; rs < 2; rs++) {
            f32x4 rm;
#pragma unroll
            for (int i = 0; i < 4; i++)
                rm[i] = fmaxf(fmaxf(s[rs][0][i], s[rs][1][i]),
                              fmaxf(s[rs][2][i], s[rs][3][i]));
#pragma unroll
            for (int m2 = 1; m2 < 16; m2 <<= 1) {
#pragma unroll
                for (int i = 0; i < 4; i++) rm[i] = fmaxf(rm[i], __shfl_xor(rm[i], m2));
            }
            f32x4 mn, corr;
#pragma unroll
            for (int i = 0; i < 4; i++) {
                mn[i] = fmaxf(mx[rs][i], rm[i]);
                corr[i] = __expf(mx[rs][i] - mn[i]);
            }
            f32x4 rsum = {};
#pragma unroll
            for (int ks = 0; ks < 4; ks++)
#pragma unroll
                for (int i = 0; i < 4; i++) {
                    float p = __expf(s[rs][ks][i] - mn[i]);
                    s[rs][ks][i] = p;
                    rsum[i] += p;
                }
#pragma unroll
            for (int m2 = 1; m2 < 16; m2 <<= 1) {
#pragma unroll
                for (int i = 0; i < 4; i++) rsum[i] += __shfl_xor(rsum[i], m2);
            }
#pragma unroll
            for (int i = 0; i < 4; i++) ls[rs][i] = ls[rs][i] * corr[i] + rsum[i];
#pragma unroll
            for (int ns = 0; ns < 4; ns++)
#pragma unroll
                for (int i = 0; i < 4; i++) o[rs][ns][i] *= corr[i];
            mx[rs] = mn;
            // write P (bf16) to per-wave LDS, swizzled
#pragma unroll
            for (int ks = 0; ks < 4; ks++)
#pragma unroll
                for (int i = 0; i < 4; i++) {
                    int prow = rs * 16 + lg * 4 + i;
                    *(u16*)((char*)&Pt[wave][0] +
                            ((prow * 128 + (ks * 16 + lr) * 2) ^ ((prow & 7) << 4))) =
                        f2bf(s[rs][ks][i]);
                }
        }
        asm volatile("s_waitcnt lgkmcnt(0)" ::: "memory");
        // PV
        bf16x8 vfr[4][2], pf[2][2];
#pragma unroll
        for (int ns = 0; ns < 4; ns++)
#pragma unroll
            for (int kstep = 0; kstep < 2; kstep++) {
                int vr = ns * 16 + lr;
                vfr[ns][kstep] = *(const bf16x8*)((char*)Vt +
                                 ((vr * 128 + kstep * 64 + lg * 16) ^ ((vr & 7) << 4)));
            }
#pragma unroll
        for (int rs = 0; rs < 2; rs++)
#pragma unroll
            for (int kstep = 0; kstep < 2; kstep++) {
                int pr = rs * 16 + lr;
                pf[rs][kstep] = *(const bf16x8*)((char*)&Pt[wave][0] +
                                ((pr * 128 + kstep * 64 + lg * 16) ^ ((pr & 7) << 4)));
            }
#pragma unroll
        for (int rs = 0; rs < 2; rs++)
#pragma unroll
            for (int ns = 0; ns < 4; ns++) {
                o[rs][ns] = __builtin_amdgcn_mfma_f32_16x16x32_bf16(pf[rs][0], vfr[ns][0],
                                                                    o[rs][ns], 0, 0, 0);
                o[rs][ns] = __builtin_amdgcn_mfma_f32_16x16x32_bf16(pf[rs][1], vfr[ns][1],
                                                                    o[rs][ns], 0, 0, 0);
            }
    }
#pragma unroll
    for (int rs = 0; rs < 2; rs++)
#pragma unroll
        for (int ns = 0; ns < 4; ns++)
#pragma unroll
            for (int i = 0; i < 4; i++) {
                int qg = qb0 + wave * 32 + rs * 16 + lg * 4 + i;
                int dk = ns * 16 + lr;
                float v = o[rs][ns][i] / ls[rs][i];
                outb[(size_t)(b * 2048 + qg) * 1024 + h * 64 + dk] = f2bf(v);
            }
}

// ---------------- fused residual add + LayerNorm ----------------
template <bool WB>
__global__ __launch_bounds__(256) void k_add_ln(const float* __restrict__ y,
                                                const float* __restrict__ resid,
                                                float* __restrict__ outf,
                                                u16* __restrict__ outb,
                                                const float* __restrict__ alpha,
                                                const float* __restrict__ beta) {
    const int row = blockIdx.x, tid = threadIdx.x;
    const f32x4 a = ((const f32x4*)(y + (size_t)row * 1024))[tid];
    const f32x4 r = ((const f32x4*)(resid + (size_t)row * 1024))[tid];
    f32x4 t;
#pragma unroll
    for (int i = 0; i < 4; i++) t[i] = a[i] + r[i];
    float s = t[0] + t[1] + t[2] + t[3];
    float ss = t[0] * t[0] + t[1] * t[1] + t[2] * t[2] + t[3] * t[3];
#pragma unroll
    for (int m2 = 1; m2 < 64; m2 <<= 1) {
        s += __shfl_xor(s, m2);
        ss += __shfl_xor(ss, m2);
    }
    __shared__ float ps[4], pss[4];
    if ((tid & 63) == 0) { ps[tid >> 6] = s; pss[tid >> 6] = ss; }
    __syncthreads();
    s = ps[0] + ps[1] + ps[2] + ps[3];
    ss = pss[0] + pss[1] + pss[2] + pss[3];
    const float mean = s * (1.f / 1024.f);
    float var = (ss - 1024.f * mean * mean) * (1.f / 1023.f);
    var = fmaxf(var, 0.f);
    const float inv = alpha[0] / (sqrtf(var) + 1e-6f);
    const float bet = beta[0];
    f32x4 oo;
#pragma unroll
    for (int i = 0; i < 4; i++) oo[i] = (t[i] - mean) * inv + bet;
    ((f32x4*)(outf + (size_t)row * 1024))[tid] = oo;
    if constexpr (WB) {
        u16x4 ob;
#pragma unroll
        for (int i = 0; i < 4; i++) ob[i] = f2bf(oo[i]);
        ((u16x4*)(outb + (size_t)row * 1024))[tid] = ob;
    }
}

// ---------------- launch ----------------
extern "C" void kernel_launch(void* const* d_in, const int* in_sizes, int n_in,
                              void* d_out, int out_size, void* d_ws, size_t ws_size,
                              hipStream_t stream) {
    const float* x   = (const float*)d_in[0];
    const int*   msk = (const int*)d_in[1];
    const float* wq  = (const float*)d_in[2];
    const float* wk  = (const float*)d_in[3];
    const float* wv  = (const float*)d_in[4];
    const float* wo  = (const float*)d_in[5];
    const float* w1  = (const float*)d_in[6];
    const float* b1  = (const float*)d_in[7];
    const float* w2  = (const float*)d_in[8];
    const float* b2  = (const float*)d_in[9];
    const float* a1  = (const float*)d_in[10];
    const float* bt1 = (const float*)d_in[11];
    const float* a2  = (const float*)d_in[12];
    const float* bt2 = (const float*)d_in[13];
    float* out = (float*)d_out;

    char* ws = (char*)d_ws;
    size_t off = 0;
    auto alloc = [&](size_t bytes) {
        void* p = ws + off;
        off += (bytes + 255) & ~(size_t)255;
        return p;
    };
    u16* xb    = (u16*)alloc((size_t)M_ * D_ * 2);        // x bf16
    u16* wqkvT = (u16*)alloc((size_t)3 * D_ * D_ * 2);    // [3072][1024]
    u16* woT   = (u16*)alloc((size_t)D_ * D_ * 2);
    u16* w1T   = (u16*)alloc((size_t)DFF_ * D_ * 2);      // [4096][1024]
    u16* w2T   = (u16*)alloc((size_t)D_ * DFF_ * 2);      // [1024][4096]
    u32* mbits = (u32*)alloc((size_t)B_ * S_ * 64 * 4);
    u16* aout  = (u16*)alloc((size_t)M_ * D_ * 2);        // attention out bf16
    float* y   = (float*)alloc((size_t)M_ * D_ * 4);      // gemm f32 out (reused)
    float* x1  = (float*)alloc((size_t)M_ * D_ * 4);      // after LN1, f32
    u16* x1b   = (u16*)alloc((size_t)M_ * D_ * 2);        // after LN1, bf16
    u16* qkv   = (u16*)alloc((size_t)M_ * DFF_ * 2);      // qkv (50MB) reused as ffn hidden (67MB)
    u16* hft   = qkv;

    // 1) pre-pass
    k_pack_mask<<<dim3((B_ * S_ * 64) / 256), 256, 0, stream>>>(msk, mbits, B_ * S_ * 64);
    k_cast_bf16<<<dim3((M_ * D_ / 4) / 256), 256, 0, stream>>>(x, xb, M_ * D_ / 4);
    dim3 tb(32, 8);
    k_transpose_cast<<<dim3(32, 32), tb, 0, stream>>>(wq, wqkvT, D_, D_);
    k_transpose_cast<<<dim3(32, 32), tb, 0, stream>>>(wk, wqkvT + D_ * D_, D_, D_);
    k_transpose_cast<<<dim3(32, 32), tb, 0, stream>>>(wv, wqkvT + 2 * D_ * D_, D_, D_);
    k_transpose_cast<<<dim3(32, 32), tb, 0, stream>>>(wo, woT, D_, D_);
    k_transpose_cast<<<dim3(128, 32), tb, 0, stream>>>(w1, w1T, D_, DFF_);
    k_transpose_cast<<<dim3(32, 128), tb, 0, stream>>>(w2, w2T, DFF_, D_);

    // 2) QKV projection (N=3072 fused), scatter to [proj][b][h][s][dk]
    k_gemm_bt<0><<<dim3(24, 64), 256, 0, stream>>>(xb, wqkvT, nullptr, qkv, nullptr,
                                                   3 * D_, D_);
    // 3) flash attention
    k_attn<<<dim3(16, 64), 256, 0, stream>>>(qkv, mbits, aout);
    // 4) output projection -> y (f32)
    k_gemm_bt<1><<<dim3(8, 64), 256, 0, stream>>>(aout, woT, y, nullptr, nullptr, D_, D_);
    // 5) LN1: x1 = LN(x + y), also bf16 copy
    k_add_ln<true><<<dim3(M_), 256, 0, stream>>>(y, x, x1, x1b, a1, bt1);
    // 6) FFN1: relu(x1 @ w1 + b1) -> hft bf16
    k_gemm_bt<2><<<dim3(32, 64), 256, 0, stream>>>(x1b, w1T, nullptr, hft, b1, DFF_, D_);
    // 7) FFN2: hft @ w2 + b2 -> y f32
    k_gemm_bt<3><<<dim3(8, 64), 256, 0, stream>>>(hft, w2T, y, nullptr, b2, D_, DFF_);
    // 8) LN2 -> d_out
    k_add_ln<false><<<dim3(M_), 256, 0, stream>>>(y, x1, out, nullptr, a2, bt2);
}

// Round 2
// 535.674 us; speedup vs baseline: 1.2035x; 1.2035x over previous
//
#include <hip/hip_runtime.h>
#include <stdint.h>

typedef __bf16 bf16x8 __attribute__((ext_vector_type(8)));
typedef float f32x4 __attribute__((ext_vector_type(4)));
typedef unsigned short u16;
typedef u16 u16x8 __attribute__((ext_vector_type(8)));
typedef u16 u16x4 __attribute__((ext_vector_type(4)));
typedef uint32_t u32;

#define DEV __device__ __forceinline__

static constexpr int B_ = 4, S_ = 2048, M_ = 8192, D_ = 1024, H_ = 16, DFF_ = 4096;

DEV u16 f2bf(float f) {
    union { float f; u32 u; } c; c.f = f;
    u32 u = c.u;
    return (u16)((u + 0x7fffu + ((u >> 16) & 1u)) >> 16);
}

DEV u32 cvt_pk_bf16(float lo, float hi) {
    u32 r;
    asm("v_cvt_pk_bf16_f32 %0, %1, %2" : "=v"(r) : "v"(lo), "v"(hi));
    return r;
}

DEV void gload16(void* lds, const void* g) {
    __builtin_amdgcn_global_load_lds(
        (const __attribute__((address_space(1))) unsigned int*)g,
        (__attribute__((address_space(3))) unsigned int*)lds, 16, 0, 0);
}

// ---------------- pre-pass kernels ----------------

__global__ __launch_bounds__(256) void k_pack_mask(const int* __restrict__ m,
                                                   u32* __restrict__ bits, int nwords) {
    int w = blockIdx.x * 256 + threadIdx.x;
    if (w >= nwords) return;
    const int4* s = (const int4*)(m + (size_t)w * 32);
    u32 r = 0;
#pragma unroll
    for (int j = 0; j < 8; j++) {
        int4 v = s[j];
        r |= (u32)(v.x != 0) << (j * 4) | (u32)(v.y != 0) << (j * 4 + 1) |
             (u32)(v.z != 0) << (j * 4 + 2) | (u32)(v.w != 0) << (j * 4 + 3);
    }
    bits[w] = r;
}

__global__ __launch_bounds__(256) void k_cast_bf16(const float* __restrict__ s,
                                                   u16* __restrict__ d, int n4) {
    int i = blockIdx.x * 256 + threadIdx.x;
    if (i >= n4) return;
    f32x4 v = ((const f32x4*)s)[i];
    u16x4 o;
    o[0] = f2bf(v[0]); o[1] = f2bf(v[1]); o[2] = f2bf(v[2]); o[3] = f2bf(v[3]);
    ((u16x4*)d)[i] = o;
}

// src [K][N] f32 -> dst [N][K] bf16
__global__ void k_transpose_cast(const float* __restrict__ s, u16* __restrict__ d,
                                 int K, int N) {
    __shared__ float t[32][33];
    int n0 = blockIdx.x * 32, k0 = blockIdx.y * 32;
    int tx = threadIdx.x, ty = threadIdx.y;
#pragma unroll
    for (int i = 0; i < 4; i++)
        t[ty + i * 8][tx] = s[(size_t)(k0 + ty + i * 8) * N + n0 + tx];
    __syncthreads();
#pragma unroll
    for (int i = 0; i < 4; i++)
        d[(size_t)(n0 + ty + i * 8) * K + k0 + tx] = f2bf(t[tx][ty + i * 8]);
}

// V [bh][s][64] (rows 128.. of qkv) -> vT [bh][64][2048]
__global__ __launch_bounds__(256) void k_transpose_v(const u16* __restrict__ qkv,
                                                     u16* __restrict__ vT) {
    __shared__ u16 t[64][68];
    const int bh = blockIdx.y, s0 = blockIdx.x * 64;
    const int r = threadIdx.x >> 2, c = (threadIdx.x & 3) * 16;
    const u16* src = qkv + ((size_t)(128 + bh) * 2048 + s0 + r) * 64 + c;
    *(u16x8*)&t[r][c] = *(const u16x8*)src;
    *(u16x8*)&t[r][c + 8] = *(const u16x8*)(src + 8);
    __syncthreads();
    u16x8 o0, o1;
#pragma unroll
    for (int e = 0; e < 8; e++) { o0[e] = t[c + e][r]; o1[e] = t[c + 8 + e][r]; }
    u16* dst = vT + ((size_t)bh * 64 + r) * 2048 + s0 + c;
    *(u16x8*)dst = o0;
    *(u16x8*)(dst + 8) = o1;
}

// ---------------- GEMM: C[M,N] = A[M,K] * Bt[N,K]^T (bf16 in, f32 acc) ----------------
// EPI 0: QKV scatter bf16 (Q pre-scaled by 1/8); 1: f32; 2: +bias, relu, bf16; 3: +bias, f32
template <int EPI>
__global__ __launch_bounds__(256) void k_gemm_bt(const u16* __restrict__ A,
                                                 const u16* __restrict__ Bt,
                                                 float* __restrict__ Cf,
                                                 u16* __restrict__ Cb,
                                                 const float* __restrict__ bias,
                                                 int N, int K) {
    __shared__ u16 As[128 * 32];
    __shared__ u16 Bs[128 * 32];
    const int tid = threadIdx.x, lane = tid & 63, wave = tid >> 6;
    const int lr = lane & 15, lg = lane >> 4;
    // bijective XCD swizzle (grids are %8==0)
    const int nwx = gridDim.x;
    const int id0 = blockIdx.y * nwx + blockIdx.x;
    const int chunk = (nwx * gridDim.y) >> 3;
    const int id = (id0 & 7) * chunk + (id0 >> 3);
    const size_t row0 = (size_t)(id / nwx) * 128;
    const int col0 = (id % nwx) * 128;
    const int wm = (wave >> 1) * 64, wn = (wave & 1) * 64;
    f32x4 acc[4][4] = {};
    for (int k0 = 0; k0 < K; k0 += 32) {
#pragma unroll
        for (int p = 0; p < 2; p++) {
            int off = p * 4096 + wave * 1024 + lane * 16;
            int r = off >> 6, cb = off & 63;
            gload16((char*)As + p * 4096 + wave * 1024,
                    (const char*)(A + (row0 + r) * K + k0) + cb);
            gload16((char*)Bs + p * 4096 + wave * 1024,
                    (const char*)(Bt + (size_t)(col0 + r) * K + k0) + cb);
        }
        __syncthreads();
        bf16x8 aF[4], bF[4];
#pragma unroll
        for (int m = 0; m < 4; m++)
            aF[m] = *(const bf16x8*)((const char*)As + (wm + m * 16 + lr) * 64 + lg * 16);
#pragma unroll
        for (int n = 0; n < 4; n++)
            bF[n] = *(const bf16x8*)((const char*)Bs + (wn + n * 16 + lr) * 64 + lg * 16);
#pragma unroll
        for (int m = 0; m < 4; m++)
#pragma unroll
            for (int n = 0; n < 4; n++)
                acc[m][n] = __builtin_amdgcn_mfma_f32_16x16x32_bf16(aF[m], bF[n],
                                                                   acc[m][n], 0, 0, 0);
        __syncthreads();
    }
#pragma unroll
    for (int m = 0; m < 4; m++)
#pragma unroll
        for (int n = 0; n < 4; n++)
#pragma unroll
            for (int i = 0; i < 4; i++) {
                int rg = (int)row0 + wm + m * 16 + lg * 4 + i;
                int cg = col0 + wn + n * 16 + lr;
                float v = acc[m][n][i];
                if constexpr (EPI == 0) {
                    if (cg < 1024) v *= 0.125f;  // fold 1/sqrt(Dk) into Q
                    int proj = cg >> 10, hh = (cg >> 6) & 15, dk = cg & 63;
                    int b = rg >> 11, s = rg & 2047;
                    size_t idx = ((size_t)(proj * 64 + b * 16 + hh) * 2048 + s) * 64 + dk;
                    Cb[idx] = f2bf(v);
                } else if constexpr (EPI == 1) {
                    Cf[(size_t)rg * N + cg] = v;
                } else if constexpr (EPI == 2) {
                    v += bias[cg];
                    v = v > 0.f ? v : 0.f;
                    Cb[(size_t)rg * N + cg] = f2bf(v);
                } else {
                    Cf[(size_t)rg * N + cg] = v + bias[cg];
                }
            }
}

// ---------------- flash attention (swapped QK^T, in-lane softmax) ----------------
// qkv: [(proj*64 + bh)][s][64] bf16 (Q pre-scaled). vT: [bh][64][2048]. out: [b*2048+s][1024].
__global__ __launch_bounds__(256) void k_attn(const u16* __restrict__ qkv,
                                              const u16* __restrict__ vT,
                                              const u32* __restrict__ mbits,
                                              u16* __restrict__ outb) {
    __shared__ u16 Kt[64 * 64];   // K tile, rows kv, swizzled
    __shared__ u16 Vt[64 * 64];   // V^T tile, rows d, swizzled
    __shared__ u16 Pt[4][32 * 64];// per-wave P rows (q-major), swizzled
    __shared__ u32 pm[128][2];
    const int tid = threadIdx.x, lane = tid & 63, wave = tid >> 6;
    const int lr = lane & 15, lg = lane >> 4;
    // XCD swizzle: grid 16 x 64 -> flat 1024, chunks of 128 share bh
    const int id0 = blockIdx.y * 16 + blockIdx.x;
    const int id = (id0 & 7) * 128 + (id0 >> 3);
    const int bh = id >> 4;
    const int b = bh >> 4, h = bh & 15;
    const int qb0 = (id & 15) * 128;
    const size_t qbase = (size_t)bh * (2048 * 64);
    const size_t kbase = (size_t)(64 + bh) * (2048 * 64);
    const size_t vtbase = (size_t)bh * (64 * 2048);

    bf16x8 qf[2][2];
    const int q0 = qb0 + wave * 32;
#pragma unroll
    for (int rs = 0; rs < 2; rs++)
#pragma unroll
        for (int kf = 0; kf < 2; kf++)
            qf[rs][kf] = *(const bf16x8*)(qkv + qbase +
                                          (size_t)(q0 + rs * 16 + lr) * 64 + kf * 32 + lg * 8);

    f32x4 o[2][4] = {};
    float mx[2] = {-1e30f, -1e30f};
    float ls[2] = {0.f, 0.f};
    const int str = tid >> 2, sq = tid & 3;
    const int swzs = (str & 7) << 4;

    for (int kv0 = 0; kv0 < 2048; kv0 += 64) {
        __syncthreads();
        {   // stage K rows (kv-major, 128B rows, XOR-swizzled)
            const u16* src = qkv + kbase + (size_t)(kv0 + str) * 64 + sq * 16;
            u16x8 v0 = *(const u16x8*)src, v1 = *(const u16x8*)(src + 8);
            int b0 = str * 128 + sq * 32;
            *(u16x8*)((char*)Kt + ((b0) ^ swzs)) = v0;
            *(u16x8*)((char*)Kt + ((b0 + 16) ^ swzs)) = v1;
        }
        {   // stage V^T rows (d-major, contiguous kv) — vectorized
            const u16* src = vT + vtbase + (size_t)str * 2048 + kv0 + sq * 16;
            u16x8 v0 = *(const u16x8*)src, v1 = *(const u16x8*)(src + 8);
            int b0 = str * 128 + sq * 32;
            *(u16x8*)((char*)Vt + ((b0) ^ swzs)) = v0;
            *(u16x8*)((char*)Vt + ((b0 + 16) ^ swzs)) = v1;
        }
        // stage mask words; each wave stages exactly the rows it consumes
        int ql = tid >> 1, wsel = tid & 1;
        u32 mword = mbits[(size_t)(b * 2048 + qb0 + ql) * 64 + (kv0 >> 5) + wsel];
        pm[ql][wsel] = mword;
        bool allones = (__ballot(mword == 0xffffffffu) == ~0ull);
        __syncthreads();

        // S^T[kv][q] = mfma(A=K rows, B=Q rows)
        f32x4 st[2][4];
#pragma unroll
        for (int ks = 0; ks < 4; ks++) {
            int rr = ks * 16 + lr;
            int rb = rr * 128, sw = (rr & 7) << 4;
            bf16x8 k0 = *(const bf16x8*)((char*)Kt + ((rb + lg * 16) ^ sw));
            bf16x8 k1 = *(const bf16x8*)((char*)Kt + ((rb + 64 + lg * 16) ^ sw));
#pragma unroll
            for (int rs = 0; rs < 2; rs++) {
                f32x4 z = {0.f, 0.f, 0.f, 0.f};
                z = __builtin_amdgcn_mfma_f32_16x16x32_bf16(k0, qf[rs][0], z, 0, 0, 0);
                z = __builtin_amdgcn_mfma_f32_16x16x32_bf16(k1, qf[rs][1], z, 0, 0, 0);
                st[rs][ks] = z;
            }
        }
        if (!allones) {
#pragma unroll
            for (int rs = 0; rs < 2; rs++) {
                u32 w0 = pm[wave * 32 + rs * 16 + lr][0];
                u32 w1 = pm[wave * 32 + rs * 16 + lr][1];
#pragma unroll
                for (int ks = 0; ks < 4; ks++)
#pragma unroll
                    for (int i = 0; i < 4; i++) {
                        int kv = ks * 16 + lg * 4 + i;
                        u32 w = (kv & 32) ? w1 : w0;
                        if (!((w >> (kv & 31)) & 1u)) st[rs][ks][i] = -1e9f;
                    }
            }
        }
        // online softmax: q = lr is lane-local; reduce over lg via 2 shuffles
#pragma unroll
        for (int rs = 0; rs < 2; rs++) {
            float m = st[rs][0][0];
#pragma unroll
            for (int ks = 0; ks < 4; ks++)
#pragma unroll
                for (int i = 0; i < 4; i++) m = fmaxf(m, st[rs][ks][i]);
            m = fmaxf(m, __shfl_xor(m, 16));
            m = fmaxf(m, __shfl_xor(m, 32));
            float mn = fmaxf(mx[rs], m);
            float corr = __expf(mx[rs] - mn);
            mx[rs] = mn;
            float sum = 0.f;
#pragma unroll
            for (int ks = 0; ks < 4; ks++)
#pragma unroll
                for (int i = 0; i < 4; i++) {
                    float p = __expf(st[rs][ks][i] - mn);
                    st[rs][ks][i] = p;
                    sum += p;
                }
            sum += __shfl_xor(sum, 16);
            sum += __shfl_xor(sum, 32);
            ls[rs] = ls[rs] * corr + sum;
#pragma unroll
            for (int ns = 0; ns < 4; ns++)
#pragma unroll
                for (int i = 0; i < 4; i++) o[rs][ns][i] *= corr;
            // pack P row (q = lr) as bf16 pairs, vectorized swizzled store
            int prow = rs * 16 + lr;
            int pb = prow * 128, swp = (prow & 7) << 4;
#pragma unroll
            for (int ks = 0; ks < 4; ks++) {
                uint2 w;
                w.x = cvt_pk_bf16(st[rs][ks][0], st[rs][ks][1]);
                w.y = cvt_pk_bf16(st[rs][ks][2], st[rs][ks][3]);
                *(uint2*)((char*)&Pt[wave][0] + ((pb + ks * 32 + lg * 8) ^ swp)) = w;
            }
        }
        // PV: O^T[d][q] += mfma(A=V^T rows, B=P rows)
        bf16x8 pf[2][2];
#pragma unroll
        for (int rs = 0; rs < 2; rs++) {
            int prow = rs * 16 + lr;
            int pb = prow * 128, swp = (prow & 7) << 4;
            pf[rs][0] = *(const bf16x8*)((char*)&Pt[wave][0] + ((pb + lg * 16) ^ swp));
            pf[rs][1] = *(const bf16x8*)((char*)&Pt[wave][0] + ((pb + 64 + lg * 16) ^ swp));
        }
#pragma unroll
        for (int ns = 0; ns < 4; ns++) {
            int vr = ns * 16 + lr;
            int vb = vr * 128, sw = (vr & 7) << 4;
            bf16x8 v0 = *(const bf16x8*)((char*)Vt + ((vb + lg * 16) ^ sw));
            bf16x8 v1 = *(const bf16x8*)((char*)Vt + ((vb + 64 + lg * 16) ^ sw));
#pragma unroll
            for (int rs = 0; rs < 2; rs++) {
                o[rs][ns] = __builtin_amdgcn_mfma_f32_16x16x32_bf16(v0, pf[rs][0],
                                                                    o[rs][ns], 0, 0, 0);
                o[rs][ns] = __builtin_amdgcn_mfma_f32_16x16x32_bf16(v1, pf[rs][1],
                                                                    o[rs][ns], 0, 0, 0);
            }
        }
    }
    // epilogue: O[q][d] = O^T[d][q] / l ; per-lane q = lr, d = ns*16+lg*4+i
#pragma unroll
    for (int rs = 0; rs < 2; rs++) {
        float inv = 1.f / ls[rs];
        int qg = qb0 + wave * 32 + rs * 16 + lr;
#pragma unroll
        for (int ns = 0; ns < 4; ns++) {
            u16x4 ov;
#pragma unroll
            for (int i = 0; i < 4; i++) ov[i] = f2bf(o[rs][ns][i] * inv);
            *(u16x4*)(outb + (size_t)(b * 2048 + qg) * 1024 + h * 64 + ns * 16 + lg * 4) = ov;
        }
    }
}

// ---------------- fused residual add + LayerNorm ----------------
template <bool WB>
__global__ __launch_bounds__(256) void k_add_ln(const float* __restrict__ y,
                                                const float* __restrict__ resid,
                                                float* __restrict__ outf,
                                                u16* __restrict__ outb,
                                                const float* __restrict__ alpha,
                                                const float* __restrict__ beta) {
    const int row = blockIdx.x, tid = threadIdx.x;
    const f32x4 a = ((const f32x4*)(y + (size_t)row * 1024))[tid];
    const f32x4 r = ((const f32x4*)(resid + (size_t)row * 1024))[tid];
    f32x4 t;
#pragma unroll
    for (int i = 0; i < 4; i++) t[i] = a[i] + r[i];
    float s = t[0] + t[1] + t[2] + t[3];
    float ss = t[0] * t[0] + t[1] * t[1] + t[2] * t[2] + t[3] * t[3];
#pragma unroll
    for (int m2 = 1; m2 < 64; m2 <<= 1) {
        s += __shfl_xor(s, m2);
        ss += __shfl_xor(ss, m2);
    }
    __shared__ float ps[4], pss[4];
    if ((tid & 63) == 0) { ps[tid >> 6] = s; pss[tid >> 6] = ss; }
    __syncthreads();
    s = ps[0] + ps[1] + ps[2] + ps[3];
    ss = pss[0] + pss[1] + pss[2] + pss[3];
    const float mean = s * (1.f / 1024.f);
    float var = (ss - 1024.f * mean * mean) * (1.f / 1023.f);
    var = fmaxf(var, 0.f);
    const float inv = alpha[0] / (sqrtf(var) + 1e-6f);
    const float bet = beta[0];
    f32x4 oo;
#pragma unroll
    for (int i = 0; i < 4; i++) oo[i] = (t[i] - mean) * inv + bet;
    ((f32x4*)(outf + (size_t)row * 1024))[tid] = oo;
    if constexpr (WB) {
        u16x4 ob;
#pragma unroll
        for (int i = 0; i < 4; i++) ob[i] = f2bf(oo[i]);
        ((u16x4*)(outb + (size_t)row * 1024))[tid] = ob;
    }
}

// ---------------- launch ----------------
extern "C" void kernel_launch(void* const* d_in, const int* in_sizes, int n_in,
                              void* d_out, int out_size, void* d_ws, size_t ws_size,
                              hipStream_t stream) {
    const float* x   = (const float*)d_in[0];
    const int*   msk = (const int*)d_in[1];
    const float* wq  = (const float*)d_in[2];
    const float* wk  = (const float*)d_in[3];
    const float* wv  = (const float*)d_in[4];
    const float* wo  = (const float*)d_in[5];
    const float* w1  = (const float*)d_in[6];
    const float* b1  = (const float*)d_in[7];
    const float* w2  = (const float*)d_in[8];
    const float* b2  = (const float*)d_in[9];
    const float* a1  = (const float*)d_in[10];
    const float* bt1 = (const float*)d_in[11];
    const float* a2  = (const float*)d_in[12];
    const float* bt2 = (const float*)d_in[13];
    float* out = (float*)d_out;

    char* ws = (char*)d_ws;
    size_t off = 0;
    auto alloc = [&](size_t bytes) {
        void* p = ws + off;
        off += (bytes + 255) & ~(size_t)255;
        return p;
    };
    u16* xb    = (u16*)alloc((size_t)M_ * D_ * 2);        // x bf16
    u16* wqkvT = (u16*)alloc((size_t)3 * D_ * D_ * 2);    // [3072][1024]
    u16* woT   = (u16*)alloc((size_t)D_ * D_ * 2);
    u16* w1T   = (u16*)alloc((size_t)DFF_ * D_ * 2);      // [4096][1024]
    u16* w2T   = (u16*)alloc((size_t)D_ * DFF_ * 2);      // [1024][4096]
    u32* mbits = (u32*)alloc((size_t)B_ * S_ * 64 * 4);
    u16* aout  = (u16*)alloc((size_t)M_ * D_ * 2);        // attention out bf16
    float* y   = (float*)alloc((size_t)M_ * D_ * 4);      // gemm f32 out (reused)
    float* x1  = (float*)alloc((size_t)M_ * D_ * 4);      // after LN1, f32
    u16* x1b   = (u16*)alloc((size_t)M_ * D_ * 2);        // after LN1, bf16
    u16* vTb   = (u16*)alloc((size_t)64 * 64 * 2048 * 2); // V^T [bh][64][2048]
    u16* qkv   = (u16*)alloc((size_t)M_ * DFF_ * 2);      // qkv (50MB) reused as ffn hidden (64MB)
    u16* hft   = qkv;

    // 1) pre-pass
    k_pack_mask<<<dim3((B_ * S_ * 64) / 256), 256, 0, stream>>>(msk, mbits, B_ * S_ * 64);
    k_cast_bf16<<<dim3((M_ * D_ / 4) / 256), 256, 0, stream>>>(x, xb, M_ * D_ / 4);
    dim3 tb(32, 8);
    k_transpose_cast<<<dim3(32, 32), tb, 0, stream>>>(wq, wqkvT, D_, D_);
    k_transpose_cast<<<dim3(32, 32), tb, 0, stream>>>(wk, wqkvT + D_ * D_, D_, D_);
    k_transpose_cast<<<dim3(32, 32), tb, 0, stream>>>(wv, wqkvT + 2 * D_ * D_, D_, D_);
    k_transpose_cast<<<dim3(32, 32), tb, 0, stream>>>(wo, woT, D_, D_);
    k_transpose_cast<<<dim3(128, 32), tb, 0, stream>>>(w1, w1T, D_, DFF_);
    k_transpose_cast<<<dim3(32, 128), tb, 0, stream>>>(w2, w2T, DFF_, D_);

    // 2) QKV projection (N=3072 fused), scatter to [proj][b][h][s][dk], Q pre-scaled
    k_gemm_bt<0><<<dim3(24, 64), 256, 0, stream>>>(xb, wqkvT, nullptr, qkv, nullptr,
                                                   3 * D_, D_);
    // 2b) V -> V^T
    k_transpose_v<<<dim3(32, 64), 256, 0, stream>>>(qkv, vTb);
    // 3) flash attention
    k_attn<<<dim3(16, 64), 256, 0, stream>>>(qkv, vTb, mbits, aout);
    // 4) output projection -> y (f32)
    k_gemm_bt<1><<<dim3(8, 64), 256, 0, stream>>>(aout, woT, y, nullptr, nullptr, D_, D_);
    // 5) LN1: x1 = LN(x + y), also bf16 copy
    k_add_ln<true><<<dim3(M_), 256, 0, stream>>>(y, x, x1, x1b, a1, bt1);
    // 6) FFN1: relu(x1 @ w1 + b1) -> hft bf16
    k_gemm_bt<2><<<dim3(32, 64), 256, 0, stream>>>(x1b, w1T, nullptr, hft, b1, DFF_, D_);
    // 7) FFN2: hft @ w2 + b2 -> y f32
    k_gemm_bt<3><<<dim3(8, 64), 256, 0, stream>>>(hft, w2T, y, nullptr, b2, D_, DFF_);
    // 8) LN2 -> d_out
    k_add_ln<false><<<dim3(M_), 256, 0, stream>>>(y, x1, out, nullptr, a2, bt2);
}

// Round 3
// 514.704 us; speedup vs baseline: 1.2525x; 1.0407x over previous
//
#include <hip/hip_runtime.h>
#include <stdint.h>

typedef __bf16 bf16x8 __attribute__((ext_vector_type(8)));
typedef float f32x4 __attribute__((ext_vector_type(4)));
typedef unsigned short u16;
typedef u16 u16x8 __attribute__((ext_vector_type(8)));
typedef u16 u16x4 __attribute__((ext_vector_type(4)));
typedef uint32_t u32;

#define DEV __device__ __forceinline__

static constexpr int B_ = 4, S_ = 2048, M_ = 8192, D_ = 1024, H_ = 16, DFF_ = 4096;

DEV u16 f2bf(float f) {
    union { float f; u32 u; } c; c.f = f;
    u32 u = c.u;
    return (u16)((u + 0x7fffu + ((u >> 16) & 1u)) >> 16);
}

DEV u32 cvt_pk_bf16(float lo, float hi) {
    u32 r;
    asm("v_cvt_pk_bf16_f32 %0, %1, %2" : "=v"(r) : "v"(lo), "v"(hi));
    return r;
}

DEV void gload16(void* lds, const void* g) {
    __builtin_amdgcn_global_load_lds(
        (const __attribute__((address_space(1))) unsigned int*)g,
        (__attribute__((address_space(3))) unsigned int*)lds, 16, 0, 0);
}

DEV bf16x8 mfma_bt(bf16x8 a, bf16x8 b);  // fwd decl unused

// ---------------- pre-pass kernels ----------------

__global__ __launch_bounds__(256) void k_pack_mask(const int* __restrict__ m,
                                                   u32* __restrict__ bits, int nwords) {
    int w = blockIdx.x * 256 + threadIdx.x;
    if (w >= nwords) return;
    const int4* s = (const int4*)(m + (size_t)w * 32);
    u32 r = 0;
#pragma unroll
    for (int j = 0; j < 8; j++) {
        int4 v = s[j];
        r |= (u32)(v.x != 0) << (j * 4) | (u32)(v.y != 0) << (j * 4 + 1) |
             (u32)(v.z != 0) << (j * 4 + 2) | (u32)(v.w != 0) << (j * 4 + 3);
    }
    bits[w] = r;
}

__global__ __launch_bounds__(256) void k_cast_bf16(const float* __restrict__ s,
                                                   u16* __restrict__ d, int n4) {
    int i = blockIdx.x * 256 + threadIdx.x;
    if (i >= n4) return;
    f32x4 v = ((const f32x4*)s)[i];
    u16x4 o;
    o[0] = f2bf(v[0]); o[1] = f2bf(v[1]); o[2] = f2bf(v[2]); o[3] = f2bf(v[3]);
    ((u16x4*)d)[i] = o;
}

// src [K][N] f32 -> dst [N][K] bf16
__global__ void k_transpose_cast(const float* __restrict__ s, u16* __restrict__ d,
                                 int K, int N) {
    __shared__ float t[32][33];
    int n0 = blockIdx.x * 32, k0 = blockIdx.y * 32;
    int tx = threadIdx.x, ty = threadIdx.y;
#pragma unroll
    for (int i = 0; i < 4; i++)
        t[ty + i * 8][tx] = s[(size_t)(k0 + ty + i * 8) * N + n0 + tx];
    __syncthreads();
#pragma unroll
    for (int i = 0; i < 4; i++)
        d[(size_t)(n0 + ty + i * 8) * K + k0 + tx] = f2bf(t[tx][ty + i * 8]);
}

// V [bh][s][64] (rows 128.. of qkv) -> vT [bh][64][2048]
__global__ __launch_bounds__(256) void k_transpose_v(const u16* __restrict__ qkv,
                                                     u16* __restrict__ vT) {
    __shared__ u16 t[64][68];
    const int bh = blockIdx.y, s0 = blockIdx.x * 64;
    const int r = threadIdx.x >> 2, c = (threadIdx.x & 3) * 16;
    const u16* src = qkv + ((size_t)(128 + bh) * 2048 + s0 + r) * 64 + c;
    *(u16x8*)&t[r][c] = *(const u16x8*)src;
    *(u16x8*)&t[r][c + 8] = *(const u16x8*)(src + 8);
    __syncthreads();
    u16x8 o0, o1;
#pragma unroll
    for (int e = 0; e < 8; e++) { o0[e] = t[c + e][r]; o1[e] = t[c + 8 + e][r]; }
    u16* dst = vT + ((size_t)bh * 64 + r) * 2048 + s0 + c;
    *(u16x8*)dst = o0;
    *(u16x8*)(dst + 8) = o1;
}

// ---- 8-wave GEMM, BK=64, dbuf LDS, counted vmcnt, T2 swizzle, setprio ----
// C[M,N] = A[M,K] * Bt[N,K]^T. BN=256 fixed, BM in {128,256}.
// EPI 0: QKV scatter bf16 (Q pre-scaled by 0.125*log2e); 1: f32; 2: +bias relu bf16; 3: +bias f32
template <int BM, int EPI>
__global__ __launch_bounds__(512, 2) void k_gemm8(const u16* __restrict__ A,
                                                  const u16* __restrict__ Bt,
                                                  float* __restrict__ Cf,
                                                  u16* __restrict__ Cb,
                                                  const float* __restrict__ bias,
                                                  int N, int K) {
    constexpr int MFR = BM / 32;   // m-fragments per wave (8 or 4)
    constexpr int ALD = BM / 64;   // A gloads per thread per K-tile
    __shared__ u16 As[2][BM * 64];
    __shared__ u16 Bs[2][256 * 64];
    const int tid = threadIdx.x, lane = tid & 63, wave = tid >> 6;
    const int lr = lane & 15, lg = lane >> 4;
    const int wm = wave >> 2, wn = wave & 3;
    const int nbx = N >> 8;
    // bijective XCD swizzle (grid %8==0)
    const int chunk = gridDim.x >> 3;
    const int id = ((int)blockIdx.x & 7) * chunk + ((int)blockIdx.x >> 3);
    const size_t row0 = (size_t)(id / nbx) * BM;
    const int col0 = (id % nbx) * 256;
    // staging geometry: chunk = 8 rows (1024B); lane covers row srow, granule (lane&7)
    const int srow = lane >> 3;
    const int sgr = (lane & 7) ^ (srow & 7);  // pre-swizzled global granule
    const int NT = K >> 6;
    f32x4 acc[MFR][4] = {};

    auto stage = [&](int buf, int t) {
#pragma unroll
        for (int i = 0; i < ALD; i++) {
            int c = i * 8 + wave;
            gload16((char*)&As[buf][0] + c * 1024,
                    (const char*)(A + (row0 + c * 8 + srow) * K + t * 64 + sgr * 8));
        }
#pragma unroll
        for (int i = 0; i < 4; i++) {
            int c = i * 8 + wave;
            gload16((char*)&Bs[buf][0] + c * 1024,
                    (const char*)(Bt + (size_t)(col0 + c * 8 + srow) * K + t * 64 + sgr * 8));
        }
    };

    stage(0, 0);
    for (int t = 0; t < NT; ++t) {
        const int cur = t & 1;
        if (t + 1 < NT) {
            stage(cur ^ 1, t + 1);
            if constexpr (BM == 256) asm volatile("s_waitcnt vmcnt(8)" ::: "memory");
            else                     asm volatile("s_waitcnt vmcnt(6)" ::: "memory");
        } else {
            asm volatile("s_waitcnt vmcnt(0)" ::: "memory");
        }
        __builtin_amdgcn_s_barrier();
        asm volatile("" ::: "memory");
        // B fragments: read once per K-tile (4n x 2ksteps)
        bf16x8 bF[4][2];
#pragma unroll
        for (int n = 0; n < 4; n++) {
            int r = wn * 64 + n * 16 + lr;
            int rb = r * 128, sw = (r & 7) << 4;
#pragma unroll
            for (int ks = 0; ks < 2; ks++)
                bF[n][ks] = *(const bf16x8*)((char*)&Bs[cur][0] +
                                             (rb + ((ks * 64 + lg * 16) ^ sw)));
        }
#pragma unroll
        for (int m = 0; m < MFR; m++) {
            int r = wm * (BM / 2) + m * 16 + lr;
            int rb = r * 128, sw = (r & 7) << 4;
            bf16x8 a0 = *(const bf16x8*)((char*)&As[cur][0] + (rb + ((lg * 16) ^ sw)));
            bf16x8 a1 = *(const bf16x8*)((char*)&As[cur][0] + (rb + ((64 + lg * 16) ^ sw)));
            __builtin_amdgcn_s_setprio(1);
#pragma unroll
            for (int n = 0; n < 4; n++) {
                acc[m][n] = __builtin_amdgcn_mfma_f32_16x16x32_bf16(a0, bF[n][0],
                                                                    acc[m][n], 0, 0, 0);
                acc[m][n] = __builtin_amdgcn_mfma_f32_16x16x32_bf16(a1, bF[n][1],
                                                                    acc[m][n], 0, 0, 0);
            }
            __builtin_amdgcn_s_setprio(0);
        }
        asm volatile("" ::: "memory");
        __builtin_amdgcn_s_barrier();
    }
#pragma unroll
    for (int m = 0; m < MFR; m++)
#pragma unroll
        for (int n = 0; n < 4; n++)
#pragma unroll
            for (int i = 0; i < 4; i++) {
                int rg = (int)row0 + wm * (BM / 2) + m * 16 + lg * 4 + i;
                int cg = col0 + wn * 64 + n * 16 + lr;
                float v = acc[m][n][i];
                if constexpr (EPI == 0) {
                    if (cg < 1024) v *= 0.1803368801111832f;  // (1/8)*log2(e)
                    int proj = cg >> 10, hh = (cg >> 6) & 15, dk = cg & 63;
                    int b = rg >> 11, s = rg & 2047;
                    size_t idx = ((size_t)(proj * 64 + b * 16 + hh) * 2048 + s) * 64 + dk;
                    Cb[idx] = f2bf(v);
                } else if constexpr (EPI == 1) {
                    Cf[(size_t)rg * N + cg] = v;
                } else if constexpr (EPI == 2) {
                    v += bias[cg];
                    v = v > 0.f ? v : 0.f;
                    Cb[(size_t)rg * N + cg] = f2bf(v);
                } else {
                    Cf[(size_t)rg * N + cg] = v + bias[cg];
                }
            }
}

// ---------------- flash attention (swapped QK^T, exp2, defer-max) ----------------
// qkv: [(proj*64 + bh)][s][64] bf16 (Q pre-scaled incl log2e). vT: [bh][64][2048].
__global__ __launch_bounds__(256) void k_attn(const u16* __restrict__ qkv,
                                              const u16* __restrict__ vT,
                                              const u32* __restrict__ mbits,
                                              u16* __restrict__ outb) {
    __shared__ u16 Kt[64 * 64];
    __shared__ u16 Vt[64 * 64];
    __shared__ u16 Pt[4][32 * 64];
    __shared__ u32 pm[128][2];
    const int tid = threadIdx.x, lane = tid & 63, wave = tid >> 6;
    const int lr = lane & 15, lg = lane >> 4;
    const int id0 = blockIdx.y * 16 + blockIdx.x;
    const int id = (id0 & 7) * 128 + (id0 >> 3);
    const int bh = id >> 4;
    const int b = bh >> 4, h = bh & 15;
    const int qb0 = (id & 15) * 128;
    const size_t qbase = (size_t)bh * (2048 * 64);
    const size_t kbase = (size_t)(64 + bh) * (2048 * 64);
    const size_t vtbase = (size_t)bh * (64 * 2048);

    bf16x8 qf[2][2];
    const int q0 = qb0 + wave * 32;
#pragma unroll
    for (int rs = 0; rs < 2; rs++)
#pragma unroll
        for (int kf = 0; kf < 2; kf++)
            qf[rs][kf] = *(const bf16x8*)(qkv + qbase +
                                          (size_t)(q0 + rs * 16 + lr) * 64 + kf * 32 + lg * 8);

    f32x4 o[2][4] = {};
    float mx[2] = {-1e30f, -1e30f};
    float ls[2] = {0.f, 0.f};
    const int str = tid >> 2, sq = tid & 3;
    const int swzs = (str & 7) << 4;

    for (int kv0 = 0; kv0 < 2048; kv0 += 64) {
        __syncthreads();
        {   // stage K rows (kv-major, 128B rows, XOR-swizzled)
            const u16* src = qkv + kbase + (size_t)(kv0 + str) * 64 + sq * 16;
            u16x8 v0 = *(const u16x8*)src, v1 = *(const u16x8*)(src + 8);
            int b0 = str * 128 + sq * 32;
            *(u16x8*)((char*)Kt + ((b0) ^ swzs)) = v0;
            *(u16x8*)((char*)Kt + ((b0 + 16) ^ swzs)) = v1;
        }
        {   // stage V^T rows (d-major, contiguous kv)
            const u16* src = vT + vtbase + (size_t)str * 2048 + kv0 + sq * 16;
            u16x8 v0 = *(const u16x8*)src, v1 = *(const u16x8*)(src + 8);
            int b0 = str * 128 + sq * 32;
            *(u16x8*)((char*)Vt + ((b0) ^ swzs)) = v0;
            *(u16x8*)((char*)Vt + ((b0 + 16) ^ swzs)) = v1;
        }
        int ql = tid >> 1, wsel = tid & 1;
        u32 mword = mbits[(size_t)(b * 2048 + qb0 + ql) * 64 + (kv0 >> 5) + wsel];
        pm[ql][wsel] = mword;
        bool allones = (__ballot(mword == 0xffffffffu) == ~0ull);
        __syncthreads();

        // S^T[kv][q] = mfma(A=K rows, B=Q rows); exp2 domain
        f32x4 st[2][4];
#pragma unroll
        for (int ks = 0; ks < 4; ks++) {
            int rr = ks * 16 + lr;
            int rb = rr * 128, sw = (rr & 7) << 4;
            bf16x8 k0 = *(const bf16x8*)((char*)Kt + ((rb + lg * 16) ^ sw));
            bf16x8 k1 = *(const bf16x8*)((char*)Kt + ((rb + 64 + lg * 16) ^ sw));
#pragma unroll
            for (int rs = 0; rs < 2; rs++) {
                f32x4 z = {0.f, 0.f, 0.f, 0.f};
                z = __builtin_amdgcn_mfma_f32_16x16x32_bf16(k0, qf[rs][0], z, 0, 0, 0);
                z = __builtin_amdgcn_mfma_f32_16x16x32_bf16(k1, qf[rs][1], z, 0, 0, 0);
                st[rs][ks] = z;
            }
        }
        if (!allones) {
#pragma unroll
            for (int rs = 0; rs < 2; rs++) {
                u32 w0 = pm[wave * 32 + rs * 16 + lr][0];
                u32 w1 = pm[wave * 32 + rs * 16 + lr][1];
#pragma unroll
                for (int ks = 0; ks < 4; ks++)
#pragma unroll
                    for (int i = 0; i < 4; i++) {
                        int kv = ks * 16 + lg * 4 + i;
                        u32 w = (kv & 32) ? w1 : w0;
                        if (!((w >> (kv & 31)) & 1u)) st[rs][ks][i] = -1e9f;
                    }
            }
        }
#pragma unroll
        for (int rs = 0; rs < 2; rs++) {
            float m = st[rs][0][0];
#pragma unroll
            for (int ks = 0; ks < 4; ks++)
#pragma unroll
                for (int i = 0; i < 4; i++) m = fmaxf(m, st[rs][ks][i]);
            m = fmaxf(m, __shfl_xor(m, 16));
            m = fmaxf(m, __shfl_xor(m, 32));
            // T13 defer-max: skip rescale while growth <= 11.5 (2^11.5 ~ 2900, safe in bf16/f32)
            if (!__all(m - mx[rs] <= 11.5f)) {
                float mn = fmaxf(mx[rs], m);
                float corr = exp2f(mx[rs] - mn);
                mx[rs] = mn;
                ls[rs] *= corr;
#pragma unroll
                for (int ns = 0; ns < 4; ns++)
#pragma unroll
                    for (int i = 0; i < 4; i++) o[rs][ns][i] *= corr;
            }
            float sum = 0.f;
#pragma unroll
            for (int ks = 0; ks < 4; ks++)
#pragma unroll
                for (int i = 0; i < 4; i++) {
                    float p = exp2f(st[rs][ks][i] - mx[rs]);
                    st[rs][ks][i] = p;
                    sum += p;
                }
            sum += __shfl_xor(sum, 16);
            sum += __shfl_xor(sum, 32);
            ls[rs] += sum;
            int prow = rs * 16 + lr;
            int pb = prow * 128, swp = (prow & 7) << 4;
#pragma unroll
            for (int ks = 0; ks < 4; ks++) {
                uint2 w;
                w.x = cvt_pk_bf16(st[rs][ks][0], st[rs][ks][1]);
                w.y = cvt_pk_bf16(st[rs][ks][2], st[rs][ks][3]);
                *(uint2*)((char*)&Pt[wave][0] + ((pb + ks * 32 + lg * 8) ^ swp)) = w;
            }
        }
        asm volatile("s_waitcnt lgkmcnt(0)" ::: "memory");
        // PV: O^T[d][q] += mfma(A=V^T rows, B=P rows)
        bf16x8 pf[2][2];
#pragma unroll
        for (int rs = 0; rs < 2; rs++) {
            int prow = rs * 16 + lr;
            int pb = prow * 128, swp = (prow & 7) << 4;
            pf[rs][0] = *(const bf16x8*)((char*)&Pt[wave][0] + ((pb + lg * 16) ^ swp));
            pf[rs][1] = *(const bf16x8*)((char*)&Pt[wave][0] + ((pb + 64 + lg * 16) ^ swp));
        }
#pragma unroll
        for (int ns = 0; ns < 4; ns++) {
            int vr = ns * 16 + lr;
            int vb = vr * 128, sw = (vr & 7) << 4;
            bf16x8 v0 = *(const bf16x8*)((char*)Vt + ((vb + lg * 16) ^ sw));
            bf16x8 v1 = *(const bf16x8*)((char*)Vt + ((vb + 64 + lg * 16) ^ sw));
#pragma unroll
            for (int rs = 0; rs < 2; rs++) {
                o[rs][ns] = __builtin_amdgcn_mfma_f32_16x16x32_bf16(v0, pf[rs][0],
                                                                    o[rs][ns], 0, 0, 0);
                o[rs][ns] = __builtin_amdgcn_mfma_f32_16x16x32_bf16(v1, pf[rs][1],
                                                                    o[rs][ns], 0, 0, 0);
            }
        }
    }
#pragma unroll
    for (int rs = 0; rs < 2; rs++) {
        float inv = 1.f / ls[rs];
        int qg = qb0 + wave * 32 + rs * 16 + lr;
#pragma unroll
        for (int ns = 0; ns < 4; ns++) {
            u16x4 ov;
#pragma unroll
            for (int i = 0; i < 4; i++) ov[i] = f2bf(o[rs][ns][i] * inv);
            *(u16x4*)(outb + (size_t)(b * 2048 + qg) * 1024 + h * 64 + ns * 16 + lg * 4) = ov;
        }
    }
}

// ---------------- fused residual add + LayerNorm ----------------
template <bool WB>
__global__ __launch_bounds__(256) void k_add_ln(const float* __restrict__ y,
                                                const float* __restrict__ resid,
                                                float* __restrict__ outf,
                                                u16* __restrict__ outb,
                                                const float* __restrict__ alpha,
                                                const float* __restrict__ beta) {
    const int row = blockIdx.x, tid = threadIdx.x;
    const f32x4 a = ((const f32x4*)(y + (size_t)row * 1024))[tid];
    const f32x4 r = ((const f32x4*)(resid + (size_t)row * 1024))[tid];
    f32x4 t;
#pragma unroll
    for (int i = 0; i < 4; i++) t[i] = a[i] + r[i];
    float s = t[0] + t[1] + t[2] + t[3];
    float ss = t[0] * t[0] + t[1] * t[1] + t[2] * t[2] + t[3] * t[3];
#pragma unroll
    for (int m2 = 1; m2 < 64; m2 <<= 1) {
        s += __shfl_xor(s, m2);
        ss += __shfl_xor(ss, m2);
    }
    __shared__ float ps[4], pss[4];
    if ((tid & 63) == 0) { ps[tid >> 6] = s; pss[tid >> 6] = ss; }
    __syncthreads();
    s = ps[0] + ps[1] + ps[2] + ps[3];
    ss = pss[0] + pss[1] + pss[2] + pss[3];
    const float mean = s * (1.f / 1024.f);
    float var = (ss - 1024.f * mean * mean) * (1.f / 1023.f);
    var = fmaxf(var, 0.f);
    const float inv = alpha[0] / (sqrtf(var) + 1e-6f);
    const float bet = beta[0];
    f32x4 oo;
#pragma unroll
    for (int i = 0; i < 4; i++) oo[i] = (t[i] - mean) * inv + bet;
    ((f32x4*)(outf + (size_t)row * 1024))[tid] = oo;
    if constexpr (WB) {
        u16x4 ob;
#pragma unroll
        for (int i = 0; i < 4; i++) ob[i] = f2bf(oo[i]);
        ((u16x4*)(outb + (size_t)row * 1024))[tid] = ob;
    }
}

// ---------------- launch ----------------
extern "C" void kernel_launch(void* const* d_in, const int* in_sizes, int n_in,
                              void* d_out, int out_size, void* d_ws, size_t ws_size,
                              hipStream_t stream) {
    const float* x   = (const float*)d_in[0];
    const int*   msk = (const int*)d_in[1];
    const float* wq  = (const float*)d_in[2];
    const float* wk  = (const float*)d_in[3];
    const float* wv  = (const float*)d_in[4];
    const float* wo  = (const float*)d_in[5];
    const float* w1  = (const float*)d_in[6];
    const float* b1  = (const float*)d_in[7];
    const float* w2  = (const float*)d_in[8];
    const float* b2  = (const float*)d_in[9];
    const float* a1  = (const float*)d_in[10];
    const float* bt1 = (const float*)d_in[11];
    const float* a2  = (const float*)d_in[12];
    const float* bt2 = (const float*)d_in[13];
    float* out = (float*)d_out;

    char* ws = (char*)d_ws;
    size_t off = 0;
    auto alloc = [&](size_t bytes) {
        void* p = ws + off;
        off += (bytes + 255) & ~(size_t)255;
        return p;
    };
    u16* xb    = (u16*)alloc((size_t)M_ * D_ * 2);
    u16* wqkvT = (u16*)alloc((size_t)3 * D_ * D_ * 2);
    u16* woT   = (u16*)alloc((size_t)D_ * D_ * 2);
    u16* w1T   = (u16*)alloc((size_t)DFF_ * D_ * 2);
    u16* w2T   = (u16*)alloc((size_t)D_ * DFF_ * 2);
    u32* mbits = (u32*)alloc((size_t)B_ * S_ * 64 * 4);
    u16* aout  = (u16*)alloc((size_t)M_ * D_ * 2);
    float* y   = (float*)alloc((size_t)M_ * D_ * 4);
    float* x1  = (float*)alloc((size_t)M_ * D_ * 4);
    u16* x1b   = (u16*)alloc((size_t)M_ * D_ * 2);
    u16* vTb   = (u16*)alloc((size_t)64 * 64 * 2048 * 2);
    u16* qkv   = (u16*)alloc((size_t)M_ * DFF_ * 2);
    u16* hft   = qkv;

    // 1) pre-pass
    k_pack_mask<<<dim3((B_ * S_ * 64) / 256), 256, 0, stream>>>(msk, mbits, B_ * S_ * 64);
    k_cast_bf16<<<dim3((M_ * D_ / 4) / 256), 256, 0, stream>>>(x, xb, M_ * D_ / 4);
    dim3 tb(32, 8);
    k_transpose_cast<<<dim3(32, 32), tb, 0, stream>>>(wq, wqkvT, D_, D_);
    k_transpose_cast<<<dim3(32, 32), tb, 0, stream>>>(wk, wqkvT + D_ * D_, D_, D_);
    k_transpose_cast<<<dim3(32, 32), tb, 0, stream>>>(wv, wqkvT + 2 * D_ * D_, D_, D_);
    k_transpose_cast<<<dim3(32, 32), tb, 0, stream>>>(wo, woT, D_, D_);
    k_transpose_cast<<<dim3(128, 32), tb, 0, stream>>>(w1, w1T, D_, DFF_);
    k_transpose_cast<<<dim3(32, 128), tb, 0, stream>>>(w2, w2T, DFF_, D_);

    // 2) QKV projection (BM=128, grid 64x12=768)
    k_gemm8<128, 0><<<dim3(768), 512, 0, stream>>>(xb, wqkvT, nullptr, qkv, nullptr,
                                                   3 * D_, D_);
    // 2b) V -> V^T
    k_transpose_v<<<dim3(32, 64), 256, 0, stream>>>(qkv, vTb);
    // 3) flash attention
    k_attn<<<dim3(16, 64), 256, 0, stream>>>(qkv, vTb, mbits, aout);
    // 4) output projection (BM=128, grid 64x4=256)
    k_gemm8<128, 1><<<dim3(256), 512, 0, stream>>>(aout, woT, y, nullptr, nullptr, D_, D_);
    // 5) LN1
    k_add_ln<true><<<dim3(M_), 256, 0, stream>>>(y, x, x1, x1b, a1, bt1);
    // 6) FFN1 (BM=256, grid 32x16=512)
    k_gemm8<256, 2><<<dim3(512), 512, 0, stream>>>(x1b, w1T, nullptr, hft, b1, DFF_, D_);
    // 7) FFN2 (BM=128, grid 64x4=256)
    k_gemm8<128, 3><<<dim3(256), 512, 0, stream>>>(hft, w2T, y, nullptr, b2, D_, DFF_);
    // 8) LN2 -> d_out
    k_add_ln<false><<<dim3(M_), 256, 0, stream>>>(y, x1, out, nullptr, a2, bt2);
}

// Round 4
// 442.741 us; speedup vs baseline: 1.4561x; 1.1625x over previous
//
#include <hip/hip_runtime.h>
#include <stdint.h>

typedef __bf16 bf16x8 __attribute__((ext_vector_type(8)));
typedef float f32x4 __attribute__((ext_vector_type(4)));
typedef unsigned short u16;
typedef u16 u16x8 __attribute__((ext_vector_type(8)));
typedef u16 u16x4 __attribute__((ext_vector_type(4)));
typedef uint32_t u32;

#define DEV __device__ __forceinline__

static constexpr int B_ = 4, S_ = 2048, M_ = 8192, D_ = 1024, H_ = 16, DFF_ = 4096;

DEV u16 f2bf(float f) {
    union { float f; u32 u; } c; c.f = f;
    u32 u = c.u;
    return (u16)((u + 0x7fffu + ((u >> 16) & 1u)) >> 16);
}

DEV u32 cvt_pk_bf16(float lo, float hi) {
    u32 r;
    asm("v_cvt_pk_bf16_f32 %0, %1, %2" : "=v"(r) : "v"(lo), "v"(hi));
    return r;
}

DEV float v_exp2(float x) {  // raw 2^x, no OCML fixup
    float r;
    asm("v_exp_f32 %0, %1" : "=v"(r) : "v"(x));
    return r;
}

DEV void gload16(void* lds, const void* g) {
    __builtin_amdgcn_global_load_lds(
        (const __attribute__((address_space(1))) unsigned int*)g,
        (__attribute__((address_space(3))) unsigned int*)lds, 16, 0, 0);
}

// ---------------- pre-pass kernels ----------------

__global__ __launch_bounds__(256) void k_pack_mask(const int* __restrict__ m,
                                                   u32* __restrict__ bits, int nwords) {
    int w = blockIdx.x * 256 + threadIdx.x;
    if (w >= nwords) return;
    const int4* s = (const int4*)(m + (size_t)w * 32);
    u32 r = 0;
#pragma unroll
    for (int j = 0; j < 8; j++) {
        int4 v = s[j];
        r |= (u32)(v.x != 0) << (j * 4) | (u32)(v.y != 0) << (j * 4 + 1) |
             (u32)(v.z != 0) << (j * 4 + 2) | (u32)(v.w != 0) << (j * 4 + 3);
    }
    bits[w] = r;
}

__global__ __launch_bounds__(256) void k_cast_bf16(const float* __restrict__ s,
                                                   u16* __restrict__ d, int n4) {
    int i = blockIdx.x * 256 + threadIdx.x;
    if (i >= n4) return;
    f32x4 v = ((const f32x4*)s)[i];
    u16x4 o;
    o[0] = f2bf(v[0]); o[1] = f2bf(v[1]); o[2] = f2bf(v[2]); o[3] = f2bf(v[3]);
    ((u16x4*)d)[i] = o;
}

// src [K][N] f32 -> dst [N][K] bf16
__global__ void k_transpose_cast(const float* __restrict__ s, u16* __restrict__ d,
                                 int K, int N) {
    __shared__ float t[32][33];
    int n0 = blockIdx.x * 32, k0 = blockIdx.y * 32;
    int tx = threadIdx.x, ty = threadIdx.y;
#pragma unroll
    for (int i = 0; i < 4; i++)
        t[ty + i * 8][tx] = s[(size_t)(k0 + ty + i * 8) * N + n0 + tx];
    __syncthreads();
#pragma unroll
    for (int i = 0; i < 4; i++)
        d[(size_t)(n0 + ty + i * 8) * K + k0 + tx] = f2bf(t[tx][ty + i * 8]);
}

// V [bh][s][64] (rows 128.. of qkv) -> vT [bh][64][2048]
__global__ __launch_bounds__(256) void k_transpose_v(const u16* __restrict__ qkv,
                                                     u16* __restrict__ vT) {
    __shared__ u16 t[64][68];
    const int bh = blockIdx.y, s0 = blockIdx.x * 64;
    const int r = threadIdx.x >> 2, c = (threadIdx.x & 3) * 16;
    const u16* src = qkv + ((size_t)(128 + bh) * 2048 + s0 + r) * 64 + c;
    *(u16x8*)&t[r][c] = *(const u16x8*)src;
    *(u16x8*)&t[r][c + 8] = *(const u16x8*)(src + 8);
    __syncthreads();
    u16x8 o0, o1;
#pragma unroll
    for (int e = 0; e < 8; e++) { o0[e] = t[c + e][r]; o1[e] = t[c + 8 + e][r]; }
    u16* dst = vT + ((size_t)bh * 64 + r) * 2048 + s0 + c;
    *(u16x8*)dst = o0;
    *(u16x8*)(dst + 8) = o1;
}

// ---- 8-wave GEMM 128x128, BK=64, dbuf LDS, counted vmcnt, T2 swizzle ----
// 2 blocks/CU (64KB LDS, <=128 VGPR). Wave tile 32x64.
// EPI 0: QKV scatter bf16 (Q pre-scaled 0.125*log2e); 1: f32; 2: +bias relu bf16; 3: +bias f32
template <int EPI>
__global__ __launch_bounds__(512, 4) void k_gemm8(const u16* __restrict__ A,
                                                  const u16* __restrict__ Bt,
                                                  float* __restrict__ Cf,
                                                  u16* __restrict__ Cb,
                                                  const float* __restrict__ bias,
                                                  int N, int K) {
    __shared__ u16 As[2][128 * 64];
    __shared__ u16 Bs[2][128 * 64];
    const int tid = threadIdx.x, lane = tid & 63, wave = tid >> 6;
    const int lr = lane & 15, lg = lane >> 4;
    const int wm = wave >> 1, wn = wave & 1;
    const int nbx = N >> 7;
    const int chunk = gridDim.x >> 3;
    const int id = ((int)blockIdx.x & 7) * chunk + ((int)blockIdx.x >> 3);
    const size_t row0 = (size_t)(id / nbx) * 128;
    const int col0 = (id % nbx) * 128;
    const int srow = lane >> 3;
    const int sgr = (lane & 7) ^ (srow & 7);  // pre-swizzled global granule
    const int NT = K >> 6;
    f32x4 acc[2][4] = {};

    auto stage = [&](int buf, int t) {
#pragma unroll
        for (int i = 0; i < 2; i++) {
            int c = i * 8 + wave;
            gload16((char*)&As[buf][0] + c * 1024,
                    (const char*)(A + (row0 + c * 8 + srow) * K + t * 64 + sgr * 8));
        }
#pragma unroll
        for (int i = 0; i < 2; i++) {
            int c = i * 8 + wave;
            gload16((char*)&Bs[buf][0] + c * 1024,
                    (const char*)(Bt + (size_t)(col0 + c * 8 + srow) * K + t * 64 + sgr * 8));
        }
    };

    stage(0, 0);
    for (int t = 0; t < NT; ++t) {
        const int cur = t & 1;
        if (t + 1 < NT) {
            stage(cur ^ 1, t + 1);
            asm volatile("s_waitcnt vmcnt(4)" ::: "memory");
        } else {
            asm volatile("s_waitcnt vmcnt(0)" ::: "memory");
        }
        __builtin_amdgcn_s_barrier();
        asm volatile("" ::: "memory");
        bf16x8 bF[4][2];
#pragma unroll
        for (int n = 0; n < 4; n++) {
            int r = wn * 64 + n * 16 + lr;
            int rb = r * 128, sw = (r & 7) << 4;
#pragma unroll
            for (int ks = 0; ks < 2; ks++)
                bF[n][ks] = *(const bf16x8*)((char*)&Bs[cur][0] +
                                             (rb + ((ks * 64 + lg * 16) ^ sw)));
        }
#pragma unroll
        for (int m = 0; m < 2; m++) {
            int r = wm * 32 + m * 16 + lr;
            int rb = r * 128, sw = (r & 7) << 4;
            bf16x8 a0 = *(const bf16x8*)((char*)&As[cur][0] + (rb + ((lg * 16) ^ sw)));
            bf16x8 a1 = *(const bf16x8*)((char*)&As[cur][0] + (rb + ((64 + lg * 16) ^ sw)));
            __builtin_amdgcn_s_setprio(1);
#pragma unroll
            for (int n = 0; n < 4; n++) {
                acc[m][n] = __builtin_amdgcn_mfma_f32_16x16x32_bf16(a0, bF[n][0],
                                                                    acc[m][n], 0, 0, 0);
                acc[m][n] = __builtin_amdgcn_mfma_f32_16x16x32_bf16(a1, bF[n][1],
                                                                    acc[m][n], 0, 0, 0);
            }
            __builtin_amdgcn_s_setprio(0);
        }
        asm volatile("" ::: "memory");
        __builtin_amdgcn_s_barrier();
    }
#pragma unroll
    for (int m = 0; m < 2; m++)
#pragma unroll
        for (int n = 0; n < 4; n++)
#pragma unroll
            for (int i = 0; i < 4; i++) {
                int rg = (int)row0 + wm * 32 + m * 16 + lg * 4 + i;
                int cg = col0 + wn * 64 + n * 16 + lr;
                float v = acc[m][n][i];
                if constexpr (EPI == 0) {
                    if (cg < 1024) v *= 0.1803368801111832f;  // (1/8)*log2(e)
                    int proj = cg >> 10, hh = (cg >> 6) & 15, dk = cg & 63;
                    int b = rg >> 11, s = rg & 2047;
                    size_t idx = ((size_t)(proj * 64 + b * 16 + hh) * 2048 + s) * 64 + dk;
                    Cb[idx] = f2bf(v);
                } else if constexpr (EPI == 1) {
                    Cf[(size_t)rg * N + cg] = v;
                } else if constexpr (EPI == 2) {
                    v += bias[cg];
                    v = v > 0.f ? v : 0.f;
                    Cb[(size_t)rg * N + cg] = f2bf(v);
                } else {
                    Cf[(size_t)rg * N + cg] = v + bias[cg];
                }
            }
}

// ------- flash attention: fixed-offset softmax (exact; shift cancels in p/l) -------
// qkv: [(proj*64 + bh)][s][64] bf16 (Q pre-scaled incl log2e). vT: [bh][64][2048].
__global__ __launch_bounds__(256) void k_attn(const u16* __restrict__ qkv,
                                              const u16* __restrict__ vT,
                                              const u32* __restrict__ mbits,
                                              u16* __restrict__ outb) {
    __shared__ u16 Kt[64 * 64];
    __shared__ u16 Vt[64 * 64];
    __shared__ u16 Pt[4][32 * 64];
    __shared__ u32 pm[128][2];
    const int tid = threadIdx.x, lane = tid & 63, wave = tid >> 6;
    const int lr = lane & 15, lg = lane >> 4;
    const int id0 = blockIdx.y * 16 + blockIdx.x;
    const int id = (id0 & 7) * 128 + (id0 >> 3);
    const int bh = id >> 4;
    const int b = bh >> 4, h = bh & 15;
    const int qb0 = (id & 15) * 128;
    const size_t qbase = (size_t)bh * (2048 * 64);
    const size_t kbase = (size_t)(64 + bh) * (2048 * 64);
    const size_t vtbase = (size_t)bh * (64 * 2048);

    bf16x8 qf[2][2];
    const int q0 = qb0 + wave * 32;
#pragma unroll
    for (int rs = 0; rs < 2; rs++)
#pragma unroll
        for (int kf = 0; kf < 2; kf++)
            qf[rs][kf] = *(const bf16x8*)(qkv + qbase +
                                          (size_t)(q0 + rs * 16 + lr) * 64 + kf * 32 + lg * 8);

    // all-ones A fragment for the l row-sum MFMA
    u16x8 ones_u;
#pragma unroll
    for (int e = 0; e < 8; e++) ones_u[e] = 0x3f80;
    const bf16x8 ones8 = *(const bf16x8*)&ones_u;

    f32x4 o[2][4] = {};
    f32x4 lacc[2] = {};
    const int str = tid >> 2, sq = tid & 3;
    const int swzs = (str & 7) << 4;
    const f32x4 zinit = {-16.f, -16.f, -16.f, -16.f};  // fixed softmax offset

    for (int kv0 = 0; kv0 < 2048; kv0 += 64) {
        __syncthreads();
        {   // stage K rows (kv-major, 128B rows, XOR-swizzled)
            const u16* src = qkv + kbase + (size_t)(kv0 + str) * 64 + sq * 16;
            u16x8 v0 = *(const u16x8*)src, v1 = *(const u16x8*)(src + 8);
            int b0 = str * 128 + sq * 32;
            *(u16x8*)((char*)Kt + ((b0) ^ swzs)) = v0;
            *(u16x8*)((char*)Kt + ((b0 + 16) ^ swzs)) = v1;
        }
        {   // stage V^T rows (d-major, contiguous kv)
            const u16* src = vT + vtbase + (size_t)str * 2048 + kv0 + sq * 16;
            u16x8 v0 = *(const u16x8*)src, v1 = *(const u16x8*)(src + 8);
            int b0 = str * 128 + sq * 32;
            *(u16x8*)((char*)Vt + ((b0) ^ swzs)) = v0;
            *(u16x8*)((char*)Vt + ((b0 + 16) ^ swzs)) = v1;
        }
        int ql = tid >> 1, wsel = tid & 1;
        u32 mword = mbits[(size_t)(b * 2048 + qb0 + ql) * 64 + (kv0 >> 5) + wsel];
        pm[ql][wsel] = mword;
        bool allones = (__ballot(mword == 0xffffffffu) == ~0ull);
        __syncthreads();

        // S'^T[kv][q] = K·Q - 16 (offset folded into C-init)
        f32x4 st[2][4];
#pragma unroll
        for (int ks = 0; ks < 4; ks++) {
            int rr = ks * 16 + lr;
            int rb = rr * 128, sw = (rr & 7) << 4;
            bf16x8 k0 = *(const bf16x8*)((char*)Kt + ((rb + lg * 16) ^ sw));
            bf16x8 k1 = *(const bf16x8*)((char*)Kt + ((rb + 64 + lg * 16) ^ sw));
#pragma unroll
            for (int rs = 0; rs < 2; rs++) {
                f32x4 z = __builtin_amdgcn_mfma_f32_16x16x32_bf16(k0, qf[rs][0],
                                                                  zinit, 0, 0, 0);
                z = __builtin_amdgcn_mfma_f32_16x16x32_bf16(k1, qf[rs][1], z, 0, 0, 0);
                st[rs][ks] = z;
            }
        }
        if (!allones) {
#pragma unroll
            for (int rs = 0; rs < 2; rs++) {
                u32 w0 = pm[wave * 32 + rs * 16 + lr][0];
                u32 w1 = pm[wave * 32 + rs * 16 + lr][1];
#pragma unroll
                for (int ks = 0; ks < 4; ks++)
#pragma unroll
                    for (int i = 0; i < 4; i++) {
                        int kv = ks * 16 + lg * 4 + i;
                        u32 w = (kv & 32) ? w1 : w0;
                        if (!((w >> (kv & 31)) & 1u)) st[rs][ks][i] = -1e9f;
                    }
            }
        }
        // p = 2^(s') ; pack to LDS (P row q = lr)
#pragma unroll
        for (int rs = 0; rs < 2; rs++) {
            int prow = rs * 16 + lr;
            int pb = prow * 128, swp = (prow & 7) << 4;
#pragma unroll
            for (int ks = 0; ks < 4; ks++) {
                uint2 w;
                w.x = cvt_pk_bf16(v_exp2(st[rs][ks][0]), v_exp2(st[rs][ks][1]));
                w.y = cvt_pk_bf16(v_exp2(st[rs][ks][2]), v_exp2(st[rs][ks][3]));
                *(uint2*)((char*)&Pt[wave][0] + ((pb + ks * 32 + lg * 8) ^ swp)) = w;
            }
        }
        asm volatile("s_waitcnt lgkmcnt(0)" ::: "memory");
        // PV + l-sum: O^T[d][q] += V^T·P ; l[q] += 1·P
        bf16x8 pf[2][2];
#pragma unroll
        for (int rs = 0; rs < 2; rs++) {
            int prow = rs * 16 + lr;
            int pb = prow * 128, swp = (prow & 7) << 4;
            pf[rs][0] = *(const bf16x8*)((char*)&Pt[wave][0] + ((pb + lg * 16) ^ swp));
            pf[rs][1] = *(const bf16x8*)((char*)&Pt[wave][0] + ((pb + 64 + lg * 16) ^ swp));
        }
#pragma unroll
        for (int rs = 0; rs < 2; rs++) {
            lacc[rs] = __builtin_amdgcn_mfma_f32_16x16x32_bf16(ones8, pf[rs][0],
                                                               lacc[rs], 0, 0, 0);
            lacc[rs] = __builtin_amdgcn_mfma_f32_16x16x32_bf16(ones8, pf[rs][1],
                                                               lacc[rs], 0, 0, 0);
        }
#pragma unroll
        for (int ns = 0; ns < 4; ns++) {
            int vr = ns * 16 + lr;
            int vb = vr * 128, sw = (vr & 7) << 4;
            bf16x8 v0 = *(const bf16x8*)((char*)Vt + ((vb + lg * 16) ^ sw));
            bf16x8 v1 = *(const bf16x8*)((char*)Vt + ((vb + 64 + lg * 16) ^ sw));
#pragma unroll
            for (int rs = 0; rs < 2; rs++) {
                o[rs][ns] = __builtin_amdgcn_mfma_f32_16x16x32_bf16(v0, pf[rs][0],
                                                                    o[rs][ns], 0, 0, 0);
                o[rs][ns] = __builtin_amdgcn_mfma_f32_16x16x32_bf16(v1, pf[rs][1],
                                                                    o[rs][ns], 0, 0, 0);
            }
        }
    }
#pragma unroll
    for (int rs = 0; rs < 2; rs++) {
        float inv = 1.f / lacc[rs][0];
        int qg = qb0 + wave * 32 + rs * 16 + lr;
#pragma unroll
        for (int ns = 0; ns < 4; ns++) {
            u16x4 ov;
#pragma unroll
            for (int i = 0; i < 4; i++) ov[i] = f2bf(o[rs][ns][i] * inv);
            *(u16x4*)(outb + (size_t)(b * 2048 + qg) * 1024 + h * 64 + ns * 16 + lg * 4) = ov;
        }
    }
}

// ---------------- fused residual add + LayerNorm ----------------
template <bool WB>
__global__ __launch_bounds__(256) void k_add_ln(const float* __restrict__ y,
                                                const float* __restrict__ resid,
                                                float* __restrict__ outf,
                                                u16* __restrict__ outb,
                                                const float* __restrict__ alpha,
                                                const float* __restrict__ beta) {
    const int row = blockIdx.x, tid = threadIdx.x;
    const f32x4 a = ((const f32x4*)(y + (size_t)row * 1024))[tid];
    const f32x4 r = ((const f32x4*)(resid + (size_t)row * 1024))[tid];
    f32x4 t;
#pragma unroll
    for (int i = 0; i < 4; i++) t[i] = a[i] + r[i];
    float s = t[0] + t[1] + t[2] + t[3];
    float ss = t[0] * t[0] + t[1] * t[1] + t[2] * t[2] + t[3] * t[3];
#pragma unroll
    for (int m2 = 1; m2 < 64; m2 <<= 1) {
        s += __shfl_xor(s, m2);
        ss += __shfl_xor(ss, m2);
    }
    __shared__ float ps[4], pss[4];
    if ((tid & 63) == 0) { ps[tid >> 6] = s; pss[tid >> 6] = ss; }
    __syncthreads();
    s = ps[0] + ps[1] + ps[2] + ps[3];
    ss = pss[0] + pss[1] + pss[2] + pss[3];
    const float mean = s * (1.f / 1024.f);
    float var = (ss - 1024.f * mean * mean) * (1.f / 1023.f);
    var = fmaxf(var, 0.f);
    const float inv = alpha[0] / (sqrtf(var) + 1e-6f);
    const float bet = beta[0];
    f32x4 oo;
#pragma unroll
    for (int i = 0; i < 4; i++) oo[i] = (t[i] - mean) * inv + bet;
    ((f32x4*)(outf + (size_t)row * 1024))[tid] = oo;
    if constexpr (WB) {
        u16x4 ob;
#pragma unroll
        for (int i = 0; i < 4; i++) ob[i] = f2bf(oo[i]);
        ((u16x4*)(outb + (size_t)row * 1024))[tid] = ob;
    }
}

// ---------------- launch ----------------
extern "C" void kernel_launch(void* const* d_in, const int* in_sizes, int n_in,
                              void* d_out, int out_size, void* d_ws, size_t ws_size,
                              hipStream_t stream) {
    const float* x   = (const float*)d_in[0];
    const int*   msk = (const int*)d_in[1];
    const float* wq  = (const float*)d_in[2];
    const float* wk  = (const float*)d_in[3];
    const float* wv  = (const float*)d_in[4];
    const float* wo  = (const float*)d_in[5];
    const float* w1  = (const float*)d_in[6];
    const float* b1  = (const float*)d_in[7];
    const float* w2  = (const float*)d_in[8];
    const float* b2  = (const float*)d_in[9];
    const float* a1  = (const float*)d_in[10];
    const float* bt1 = (const float*)d_in[11];
    const float* a2  = (const float*)d_in[12];
    const float* bt2 = (const float*)d_in[13];
    float* out = (float*)d_out;

    char* ws = (char*)d_ws;
    size_t off = 0;
    auto alloc = [&](size_t bytes) {
        void* p = ws + off;
        off += (bytes + 255) & ~(size_t)255;
        return p;
    };
    u16* xb    = (u16*)alloc((size_t)M_ * D_ * 2);
    u16* wqkvT = (u16*)alloc((size_t)3 * D_ * D_ * 2);
    u16* woT   = (u16*)alloc((size_t)D_ * D_ * 2);
    u16* w1T   = (u16*)alloc((size_t)DFF_ * D_ * 2);
    u16* w2T   = (u16*)alloc((size_t)D_ * DFF_ * 2);
    u32* mbits = (u32*)alloc((size_t)B_ * S_ * 64 * 4);
    u16* aout  = (u16*)alloc((size_t)M_ * D_ * 2);
    float* y   = (float*)alloc((size_t)M_ * D_ * 4);
    float* x1  = (float*)alloc((size_t)M_ * D_ * 4);
    u16* x1b   = (u16*)alloc((size_t)M_ * D_ * 2);
    u16* vTb   = (u16*)alloc((size_t)64 * 64 * 2048 * 2);
    u16* qkv   = (u16*)alloc((size_t)M_ * DFF_ * 2);
    u16* hft   = qkv;

    // 1) pre-pass
    k_pack_mask<<<dim3((B_ * S_ * 64) / 256), 256, 0, stream>>>(msk, mbits, B_ * S_ * 64);
    k_cast_bf16<<<dim3((M_ * D_ / 4) / 256), 256, 0, stream>>>(x, xb, M_ * D_ / 4);
    dim3 tb(32, 8);
    k_transpose_cast<<<dim3(32, 32), tb, 0, stream>>>(wq, wqkvT, D_, D_);
    k_transpose_cast<<<dim3(32, 32), tb, 0, stream>>>(wk, wqkvT + D_ * D_, D_, D_);
    k_transpose_cast<<<dim3(32, 32), tb, 0, stream>>>(wv, wqkvT + 2 * D_ * D_, D_, D_);
    k_transpose_cast<<<dim3(32, 32), tb, 0, stream>>>(wo, woT, D_, D_);
    k_transpose_cast<<<dim3(128, 32), tb, 0, stream>>>(w1, w1T, D_, DFF_);
    k_transpose_cast<<<dim3(32, 128), tb, 0, stream>>>(w2, w2T, DFF_, D_);

    // 2) QKV projection (grid 64x24=1536)
    k_gemm8<0><<<dim3(1536), 512, 0, stream>>>(xb, wqkvT, nullptr, qkv, nullptr,
                                               3 * D_, D_);
    // 2b) V -> V^T
    k_transpose_v<<<dim3(32, 64), 256, 0, stream>>>(qkv, vTb);
    // 3) flash attention
    k_attn<<<dim3(16, 64), 256, 0, stream>>>(qkv, vTb, mbits, aout);
    // 4) output projection (grid 64x8=512)
    k_gemm8<1><<<dim3(512), 512, 0, stream>>>(aout, woT, y, nullptr, nullptr, D_, D_);
    // 5) LN1
    k_add_ln<true><<<dim3(M_), 256, 0, stream>>>(y, x, x1, x1b, a1, bt1);
    // 6) FFN1 (grid 64x32=2048)
    k_gemm8<2><<<dim3(2048), 512, 0, stream>>>(x1b, w1T, nullptr, hft, b1, DFF_, D_);
    // 7) FFN2 (grid 64x8=512)
    k_gemm8<3><<<dim3(512), 512, 0, stream>>>(hft, w2T, y, nullptr, b2, D_, DFF_);
    // 8) LN2 -> d_out
    k_add_ln<false><<<dim3(M_), 256, 0, stream>>>(y, x1, out, nullptr, a2, bt2);
}

// Round 5
// 420.069 us; speedup vs baseline: 1.5347x; 1.0540x over previous
//
#include <hip/hip_runtime.h>
#include <stdint.h>

typedef __bf16 bf16x8 __attribute__((ext_vector_type(8)));
typedef float f32x4 __attribute__((ext_vector_type(4)));
typedef unsigned short u16;
typedef u16 u16x8 __attribute__((ext_vector_type(8)));
typedef u16 u16x4 __attribute__((ext_vector_type(4)));
typedef uint32_t u32;

#define DEV __device__ __forceinline__
#define MFMA(a, b, c) __builtin_amdgcn_mfma_f32_16x16x32_bf16(a, b, c, 0, 0, 0)

static constexpr int B_ = 4, S_ = 2048, M_ = 8192, D_ = 1024, H_ = 16, DFF_ = 4096;

DEV u16 f2bf(float f) {
    union { float f; u32 u; } c; c.f = f;
    u32 u = c.u;
    return (u16)((u + 0x7fffu + ((u >> 16) & 1u)) >> 16);
}

DEV u32 cvt_pk_bf16(float lo, float hi) {
    u32 r;
    asm("v_cvt_pk_bf16_f32 %0, %1, %2" : "=v"(r) : "v"(lo), "v"(hi));
    return r;
}

DEV float v_exp2(float x) {  // raw 2^x
    float r;
    asm("v_exp_f32 %0, %1" : "=v"(r) : "v"(x));
    return r;
}

DEV void gload16(void* lds, const void* g) {
    __builtin_amdgcn_global_load_lds(
        (const __attribute__((address_space(1))) unsigned int*)g,
        (__attribute__((address_space(3))) unsigned int*)lds, 16, 0, 0);
}

// ---------------- pre-pass kernels ----------------

__global__ __launch_bounds__(256) void k_pack_mask(const int* __restrict__ m,
                                                   u32* __restrict__ bits, int nwords) {
    int w = blockIdx.x * 256 + threadIdx.x;
    if (w >= nwords) return;
    const int4* s = (const int4*)(m + (size_t)w * 32);
    u32 r = 0;
#pragma unroll
    for (int j = 0; j < 8; j++) {
        int4 v = s[j];
        r |= (u32)(v.x != 0) << (j * 4) | (u32)(v.y != 0) << (j * 4 + 1) |
             (u32)(v.z != 0) << (j * 4 + 2) | (u32)(v.w != 0) << (j * 4 + 3);
    }
    bits[w] = r;
}

__global__ __launch_bounds__(256) void k_cast_bf16(const float* __restrict__ s,
                                                   u16* __restrict__ d, int n4) {
    int i = blockIdx.x * 256 + threadIdx.x;
    if (i >= n4) return;
    f32x4 v = ((const f32x4*)s)[i];
    u16x4 o;
    o[0] = f2bf(v[0]); o[1] = f2bf(v[1]); o[2] = f2bf(v[2]); o[3] = f2bf(v[3]);
    ((u16x4*)d)[i] = o;
}

// src [K][N] f32 -> dst [N][K] bf16
__global__ void k_transpose_cast(const float* __restrict__ s, u16* __restrict__ d,
                                 int K, int N) {
    __shared__ float t[32][33];
    int n0 = blockIdx.x * 32, k0 = blockIdx.y * 32;
    int tx = threadIdx.x, ty = threadIdx.y;
#pragma unroll
    for (int i = 0; i < 4; i++)
        t[ty + i * 8][tx] = s[(size_t)(k0 + ty + i * 8) * N + n0 + tx];
    __syncthreads();
#pragma unroll
    for (int i = 0; i < 4; i++)
        d[(size_t)(n0 + ty + i * 8) * K + k0 + tx] = f2bf(t[tx][ty + i * 8]);
}

// V [bh][s][64] (rows 128.. of qkv) -> vT [bh][64][2048]
__global__ __launch_bounds__(256) void k_transpose_v(const u16* __restrict__ qkv,
                                                     u16* __restrict__ vT) {
    __shared__ u16 t[64][68];
    const int bh = blockIdx.y, s0 = blockIdx.x * 64;
    const int r = threadIdx.x >> 2, c = (threadIdx.x & 3) * 16;
    const u16* src = qkv + ((size_t)(128 + bh) * 2048 + s0 + r) * 64 + c;
    *(u16x8*)&t[r][c] = *(const u16x8*)src;
    *(u16x8*)&t[r][c + 8] = *(const u16x8*)(src + 8);
    __syncthreads();
    u16x8 o0, o1;
#pragma unroll
    for (int e = 0; e < 8; e++) { o0[e] = t[c + e][r]; o1[e] = t[c + 8 + e][r]; }
    u16* dst = vT + ((size_t)bh * 64 + r) * 2048 + s0 + c;
    *(u16x8*)dst = o0;
    *(u16x8*)(dst + 8) = o1;
}

// ---- 256x256 8-wave 4-phase GEMM, BK=64, dbuf LDS, counted vmcnt ----
// Wave tile 128x64 (2M x 4N). 64 MFMA / 24 ds_read_b128 per K-tile.
// Phase ledger (tile t, cur=t&1, nxt=cur^1):
//  P0: rd A-mh0(8)+B-nh0(4); stage Ah0(t+1)->nxt; bar; Q0; bar
//  P1: rd B-nh1(4);          stage Ah1(t+1)->nxt; bar; Q1; bar
//  P2: rd A-mh1(8);          stage Bh0(t+2)->cur; bar; Q2; bar
//  P3:                       stage Bh1(t+2)->cur; vmcnt(4|0); bar; Q3; bar
// Every staged region's last reader drained >=1 barrier before the stage.
template <int EPI>
__global__ __launch_bounds__(512, 2) void k_gemm256(const u16* __restrict__ A,
                                                    const u16* __restrict__ Bt,
                                                    float* __restrict__ Cf,
                                                    u16* __restrict__ Cb,
                                                    const float* __restrict__ bias,
                                                    int N, int K) {
    __shared__ u16 As[2][256 * 64];
    __shared__ u16 Bs[2][256 * 64];
    const int tid = threadIdx.x, lane = tid & 63, wave = tid >> 6;
    const int lr = lane & 15, lg = lane >> 4;
    const int wm = wave >> 2, wn = wave & 3;
    const int nbx = N >> 8;
    const int chunk = gridDim.x >> 3;
    const int id = ((int)blockIdx.x & 7) * chunk + ((int)blockIdx.x >> 3);
    const size_t row0 = (size_t)(id / nbx) * 256;
    const int col0 = (id % nbx) * 256;
    const int srow = lane >> 3;
    const int sgr = (lane & 7) ^ srow;  // pre-swizzled global granule
    const int NT = K >> 6;
    f32x4 acc[8][4] = {};

    auto stage_half = [&](int isB, int buf, int t, int h) {
        const u16* g = isB ? Bt : A;
        const size_t grow0 = isB ? (size_t)col0 : row0;
        char* base = isB ? (char*)&Bs[buf][0] : (char*)&As[buf][0];
#pragma unroll
        for (int l = 0; l < 2; l++) {
            int rt = h * 128 + l * 64 + wave * 8;
            gload16(base + rt * 128,
                    (const char*)(g + (grow0 + rt + srow) * K + t * 64 + sgr * 8));
        }
    };
    auto rdA = [&](int cur, int mh, int m, int kk) -> bf16x8 {
        int r = wm * 128 + mh * 64 + m * 16 + lr;
        int gi = kk * 4 + lg;
        return *(const bf16x8*)((char*)&As[cur][0] + r * 128 + ((gi ^ (r & 7)) << 4));
    };
    auto rdB = [&](int cur, int nh, int n, int kk) -> bf16x8 {
        int r = wn * 64 + nh * 32 + n * 16 + lr;
        int gi = kk * 4 + lg;
        return *(const bf16x8*)((char*)&Bs[cur][0] + r * 128 + ((gi ^ (r & 7)) << 4));
    };

    // prologue: tile0 (4 halves) + tile1 B halves; verify tile0
    stage_half(0, 0, 0, 0); stage_half(0, 0, 0, 1);
    stage_half(1, 0, 0, 0); stage_half(1, 0, 0, 1);
    stage_half(1, 1, 1, 0); stage_half(1, 1, 1, 1);
    asm volatile("s_waitcnt vmcnt(4)" ::: "memory");
    __builtin_amdgcn_s_barrier();

    bf16x8 aF[4][2], b0F[2][2], b1F[2][2];
    for (int t = 0; t < NT; ++t) {
        const int cur = t & 1, nxt = cur ^ 1;
        // ---- P0 ----
#pragma unroll
        for (int m = 0; m < 4; m++) { aF[m][0] = rdA(cur, 0, m, 0); aF[m][1] = rdA(cur, 0, m, 1); }
#pragma unroll
        for (int n = 0; n < 2; n++) { b0F[n][0] = rdB(cur, 0, n, 0); b0F[n][1] = rdB(cur, 0, n, 1); }
        if (t + 1 < NT) stage_half(0, nxt, t + 1, 0);
        __builtin_amdgcn_s_barrier();
        asm volatile("s_waitcnt lgkmcnt(0)" ::: "memory");
        __builtin_amdgcn_sched_barrier(0);
        __builtin_amdgcn_s_setprio(1);
#pragma unroll
        for (int m = 0; m < 4; m++)
#pragma unroll
            for (int n = 0; n < 2; n++) {
                acc[m][n] = MFMA(aF[m][0], b0F[n][0], acc[m][n]);
                acc[m][n] = MFMA(aF[m][1], b0F[n][1], acc[m][n]);
            }
        __builtin_amdgcn_s_setprio(0);
        __builtin_amdgcn_s_barrier();
        // ---- P1 ----
#pragma unroll
        for (int n = 0; n < 2; n++) { b1F[n][0] = rdB(cur, 1, n, 0); b1F[n][1] = rdB(cur, 1, n, 1); }
        if (t + 1 < NT) stage_half(0, nxt, t + 1, 1);
        __builtin_amdgcn_s_barrier();
        asm volatile("s_waitcnt lgkmcnt(0)" ::: "memory");
        __builtin_amdgcn_sched_barrier(0);
        __builtin_amdgcn_s_setprio(1);
#pragma unroll
        for (int m = 0; m < 4; m++)
#pragma unroll
            for (int n = 0; n < 2; n++) {
                acc[m][2 + n] = MFMA(aF[m][0], b1F[n][0], acc[m][2 + n]);
                acc[m][2 + n] = MFMA(aF[m][1], b1F[n][1], acc[m][2 + n]);
            }
        __builtin_amdgcn_s_setprio(0);
        __builtin_amdgcn_s_barrier();
        // ---- P2 ----
#pragma unroll
        for (int m = 0; m < 4; m++) { aF[m][0] = rdA(cur, 1, m, 0); aF[m][1] = rdA(cur, 1, m, 1); }
        if (t + 2 < NT) stage_half(1, cur, t + 2, 0);
        __builtin_amdgcn_s_barrier();
        asm volatile("s_waitcnt lgkmcnt(0)" ::: "memory");
        __builtin_amdgcn_sched_barrier(0);
        __builtin_amdgcn_s_setprio(1);
#pragma unroll
        for (int m = 0; m < 4; m++)
#pragma unroll
            for (int n = 0; n < 2; n++) {
                acc[4 + m][2 + n] = MFMA(aF[m][0], b1F[n][0], acc[4 + m][2 + n]);
                acc[4 + m][2 + n] = MFMA(aF[m][1], b1F[n][1], acc[4 + m][2 + n]);
            }
        __builtin_amdgcn_s_setprio(0);
        __builtin_amdgcn_s_barrier();
        // ---- P3 ----
        if (t + 2 < NT) stage_half(1, cur, t + 2, 1);
        if (t + 1 < NT) {
            if (t + 2 < NT) asm volatile("s_waitcnt vmcnt(4)" ::: "memory");
            else            asm volatile("s_waitcnt vmcnt(0)" ::: "memory");
        }
        __builtin_amdgcn_s_barrier();
        __builtin_amdgcn_s_setprio(1);
#pragma unroll
        for (int m = 0; m < 4; m++)
#pragma unroll
            for (int n = 0; n < 2; n++) {
                acc[4 + m][n] = MFMA(aF[m][0], b0F[n][0], acc[4 + m][n]);
                acc[4 + m][n] = MFMA(aF[m][1], b0F[n][1], acc[4 + m][n]);
            }
        __builtin_amdgcn_s_setprio(0);
        __builtin_amdgcn_s_barrier();
    }
#pragma unroll
    for (int m = 0; m < 8; m++)
#pragma unroll
        for (int n = 0; n < 4; n++)
#pragma unroll
            for (int i = 0; i < 4; i++) {
                int rg = (int)row0 + wm * 128 + m * 16 + lg * 4 + i;
                int cg = col0 + wn * 64 + n * 16 + lr;
                float v = acc[m][n][i];
                if constexpr (EPI == 0) {
                    if (cg < 1024) v *= 0.1803368801111832f;  // (1/8)*log2(e)
                    int proj = cg >> 10, hh = (cg >> 6) & 15, dk = cg & 63;
                    int b = rg >> 11, s = rg & 2047;
                    size_t idx = ((size_t)(proj * 64 + b * 16 + hh) * 2048 + s) * 64 + dk;
                    Cb[idx] = f2bf(v);
                } else if constexpr (EPI == 1) {
                    Cf[(size_t)rg * N + cg] = v;
                } else if constexpr (EPI == 2) {
                    v += bias[cg];
                    v = v > 0.f ? v : 0.f;
                    Cb[(size_t)rg * N + cg] = f2bf(v);
                } else {
                    Cf[(size_t)rg * N + cg] = v + bias[cg];
                }
            }
}

// ---- 128x128 8-wave GEMM (kept for N=1024 ops: WO, FFN2) ----
template <int EPI>
__global__ __launch_bounds__(512, 4) void k_gemm8(const u16* __restrict__ A,
                                                  const u16* __restrict__ Bt,
                                                  float* __restrict__ Cf,
                                                  u16* __restrict__ Cb,
                                                  const float* __restrict__ bias,
                                                  int N, int K) {
    __shared__ u16 As[2][128 * 64];
    __shared__ u16 Bs[2][128 * 64];
    const int tid = threadIdx.x, lane = tid & 63, wave = tid >> 6;
    const int lr = lane & 15, lg = lane >> 4;
    const int wm = wave >> 1, wn = wave & 1;
    const int nbx = N >> 7;
    const int chunk = gridDim.x >> 3;
    const int id = ((int)blockIdx.x & 7) * chunk + ((int)blockIdx.x >> 3);
    const size_t row0 = (size_t)(id / nbx) * 128;
    const int col0 = (id % nbx) * 128;
    const int srow = lane >> 3;
    const int sgr = (lane & 7) ^ srow;
    const int NT = K >> 6;
    f32x4 acc[2][4] = {};

    auto stage = [&](int buf, int t) {
#pragma unroll
        for (int i = 0; i < 2; i++) {
            int c = i * 8 + wave;
            gload16((char*)&As[buf][0] + c * 1024,
                    (const char*)(A + (row0 + c * 8 + srow) * K + t * 64 + sgr * 8));
        }
#pragma unroll
        for (int i = 0; i < 2; i++) {
            int c = i * 8 + wave;
            gload16((char*)&Bs[buf][0] + c * 1024,
                    (const char*)(Bt + (size_t)(col0 + c * 8 + srow) * K + t * 64 + sgr * 8));
        }
    };

    stage(0, 0);
    for (int t = 0; t < NT; ++t) {
        const int cur = t & 1;
        if (t + 1 < NT) {
            stage(cur ^ 1, t + 1);
            asm volatile("s_waitcnt vmcnt(4)" ::: "memory");
        } else {
            asm volatile("s_waitcnt vmcnt(0)" ::: "memory");
        }
        __builtin_amdgcn_s_barrier();
        asm volatile("" ::: "memory");
        bf16x8 bF[4][2];
#pragma unroll
        for (int n = 0; n < 4; n++) {
            int r = wn * 64 + n * 16 + lr;
            int rb = r * 128, sw = (r & 7) << 4;
#pragma unroll
            for (int ks = 0; ks < 2; ks++)
                bF[n][ks] = *(const bf16x8*)((char*)&Bs[cur][0] +
                                             (rb + ((ks * 64 + lg * 16) ^ sw)));
        }
#pragma unroll
        for (int m = 0; m < 2; m++) {
            int r = wm * 32 + m * 16 + lr;
            int rb = r * 128, sw = (r & 7) << 4;
            bf16x8 a0 = *(const bf16x8*)((char*)&As[cur][0] + (rb + ((lg * 16) ^ sw)));
            bf16x8 a1 = *(const bf16x8*)((char*)&As[cur][0] + (rb + ((64 + lg * 16) ^ sw)));
            __builtin_amdgcn_s_setprio(1);
#pragma unroll
            for (int n = 0; n < 4; n++) {
                acc[m][n] = MFMA(a0, bF[n][0], acc[m][n]);
                acc[m][n] = MFMA(a1, bF[n][1], acc[m][n]);
            }
            __builtin_amdgcn_s_setprio(0);
        }
        asm volatile("" ::: "memory");
        __builtin_amdgcn_s_barrier();
    }
#pragma unroll
    for (int m = 0; m < 2; m++)
#pragma unroll
        for (int n = 0; n < 4; n++)
#pragma unroll
            for (int i = 0; i < 4; i++) {
                int rg = (int)row0 + wm * 32 + m * 16 + lg * 4 + i;
                int cg = col0 + wn * 64 + n * 16 + lr;
                float v = acc[m][n][i];
                if constexpr (EPI == 0) {
                    if (cg < 1024) v *= 0.1803368801111832f;
                    int proj = cg >> 10, hh = (cg >> 6) & 15, dk = cg & 63;
                    int b = rg >> 11, s = rg & 2047;
                    size_t idx = ((size_t)(proj * 64 + b * 16 + hh) * 2048 + s) * 64 + dk;
                    Cb[idx] = f2bf(v);
                } else if constexpr (EPI == 1) {
                    Cf[(size_t)rg * N + cg] = v;
                } else if constexpr (EPI == 2) {
                    v += bias[cg];
                    v = v > 0.f ? v : 0.f;
                    Cb[(size_t)rg * N + cg] = f2bf(v);
                } else {
                    Cf[(size_t)rg * N + cg] = v + bias[cg];
                }
            }
}

// ------- flash attention: fixed-offset softmax + T14 async-stage dbuf -------
// qkv: [(proj*64 + bh)][s][64] bf16 (Q pre-scaled incl log2e). vT: [bh][64][2048].
__global__ __launch_bounds__(256) void k_attn(const u16* __restrict__ qkv,
                                              const u16* __restrict__ vT,
                                              const u32* __restrict__ mbits,
                                              u16* __restrict__ outb) {
    __shared__ u16 Kt[2][64 * 64];
    __shared__ u16 Vt[2][64 * 64];
    __shared__ u16 Pt[4][32 * 64];
    __shared__ u32 pm[2][128][2];
    const int tid = threadIdx.x, lane = tid & 63, wave = tid >> 6;
    const int lr = lane & 15, lg = lane >> 4;
    const int id0 = blockIdx.y * 16 + blockIdx.x;
    const int id = (id0 & 7) * 128 + (id0 >> 3);
    const int bh = id >> 4;
    const int b = bh >> 4, h = bh & 15;
    const int qb0 = (id & 15) * 128;
    const size_t qbase = (size_t)bh * (2048 * 64);
    const size_t kbase = (size_t)(64 + bh) * (2048 * 64);
    const size_t vtbase = (size_t)bh * (64 * 2048);

    bf16x8 qf[2][2];
    const int q0 = qb0 + wave * 32;
#pragma unroll
    for (int rs = 0; rs < 2; rs++)
#pragma unroll
        for (int kf = 0; kf < 2; kf++)
            qf[rs][kf] = *(const bf16x8*)(qkv + qbase +
                                          (size_t)(q0 + rs * 16 + lr) * 64 + kf * 32 + lg * 8);

    u16x8 ones_u;
#pragma unroll
    for (int e = 0; e < 8; e++) ones_u[e] = 0x3f80;
    const bf16x8 ones8 = *(const bf16x8*)&ones_u;

    f32x4 o[2][4] = {};
    f32x4 lacc[2] = {};
    const int str = tid >> 2, sq = tid & 3;
    const int swzs = (str & 7) << 4;
    const f32x4 zinit = {-16.f, -16.f, -16.f, -16.f};

    u16x8 krA, krB, vrA, vrB; u32 mwA;
    auto issue_loads = [&](int kv0n) {
        const u16* ksrc = qkv + kbase + (size_t)(kv0n + str) * 64 + sq * 16;
        krA = *(const u16x8*)ksrc; krB = *(const u16x8*)(ksrc + 8);
        const u16* vsrc = vT + vtbase + (size_t)str * 2048 + kv0n + sq * 16;
        vrA = *(const u16x8*)vsrc; vrB = *(const u16x8*)(vsrc + 8);
        mwA = mbits[(size_t)(b * 2048 + qb0 + (tid >> 1)) * 64 + (kv0n >> 5) + (tid & 1)];
    };
    auto write_tile = [&](int buf) -> bool {
        int b0 = str * 128 + sq * 32;
        *(u16x8*)((char*)&Kt[buf][0] + ((b0) ^ swzs)) = krA;
        *(u16x8*)((char*)&Kt[buf][0] + ((b0 + 16) ^ swzs)) = krB;
        *(u16x8*)((char*)&Vt[buf][0] + ((b0) ^ swzs)) = vrA;
        *(u16x8*)((char*)&Vt[buf][0] + ((b0 + 16) ^ swzs)) = vrB;
        pm[buf][tid >> 1][tid & 1] = mwA;
        return (__ballot(mwA == 0xffffffffu) == ~0ull);
    };

    issue_loads(0);
    bool aon_nxt = write_tile(0);
    for (int t = 0; t < 32; ++t) {
        const int cur = t & 1;
        const bool aon = aon_nxt ||
                         false;  // tile t's all-ones flag (carried)
        bool aon_cur = aon_nxt;
        if (t + 1 < 32) issue_loads((t + 1) * 64);
        asm volatile("s_waitcnt lgkmcnt(0)" ::: "memory");
        __builtin_amdgcn_s_barrier();
        (void)aon;

        // S'^T[kv][q] = K·Q - 16
        f32x4 st[2][4];
#pragma unroll
        for (int ks = 0; ks < 4; ks++) {
            int rr = ks * 16 + lr;
            int rb = rr * 128, sw = (rr & 7) << 4;
            bf16x8 k0 = *(const bf16x8*)((char*)&Kt[cur][0] + ((rb + lg * 16) ^ sw));
            bf16x8 k1 = *(const bf16x8*)((char*)&Kt[cur][0] + ((rb + 64 + lg * 16) ^ sw));
#pragma unroll
            for (int rs = 0; rs < 2; rs++) {
                f32x4 z = MFMA(k0, qf[rs][0], zinit);
                z = MFMA(k1, qf[rs][1], z);
                st[rs][ks] = z;
            }
        }
        if (!aon_cur) {
#pragma unroll
            for (int rs = 0; rs < 2; rs++) {
                u32 w0 = pm[cur][wave * 32 + rs * 16 + lr][0];
                u32 w1 = pm[cur][wave * 32 + rs * 16 + lr][1];
#pragma unroll
                for (int ks = 0; ks < 4; ks++)
#pragma unroll
                    for (int i = 0; i < 4; i++) {
                        int kv = ks * 16 + lg * 4 + i;
                        u32 w = (kv & 32) ? w1 : w0;
                        if (!((w >> (kv & 31)) & 1u)) st[rs][ks][i] = -1e9f;
                    }
            }
        }
        // p = 2^(s'); pack to per-wave LDS
#pragma unroll
        for (int rs = 0; rs < 2; rs++) {
            int prow = rs * 16 + lr;
            int pb = prow * 128, swp = (prow & 7) << 4;
#pragma unroll
            for (int ks = 0; ks < 4; ks++) {
                uint2 w;
                w.x = cvt_pk_bf16(v_exp2(st[rs][ks][0]), v_exp2(st[rs][ks][1]));
                w.y = cvt_pk_bf16(v_exp2(st[rs][ks][2]), v_exp2(st[rs][ks][3]));
                *(uint2*)((char*)&Pt[wave][0] + ((pb + ks * 32 + lg * 8) ^ swp)) = w;
            }
        }
        asm volatile("s_waitcnt lgkmcnt(0)" ::: "memory");
        __builtin_amdgcn_sched_barrier(0);
        // PV + l-sum
        bf16x8 pf[2][2];
#pragma unroll
        for (int rs = 0; rs < 2; rs++) {
            int prow = rs * 16 + lr;
            int pb = prow * 128, swp = (prow & 7) << 4;
            pf[rs][0] = *(const bf16x8*)((char*)&Pt[wave][0] + ((pb + lg * 16) ^ swp));
            pf[rs][1] = *(const bf16x8*)((char*)&Pt[wave][0] + ((pb + 64 + lg * 16) ^ swp));
        }
#pragma unroll
        for (int rs = 0; rs < 2; rs++) {
            lacc[rs] = MFMA(ones8, pf[rs][0], lacc[rs]);
            lacc[rs] = MFMA(ones8, pf[rs][1], lacc[rs]);
        }
#pragma unroll
        for (int ns = 0; ns < 4; ns++) {
            int vr = ns * 16 + lr;
            int vb = vr * 128, sw = (vr & 7) << 4;
            bf16x8 v0 = *(const bf16x8*)((char*)&Vt[cur][0] + ((vb + lg * 16) ^ sw));
            bf16x8 v1 = *(const bf16x8*)((char*)&Vt[cur][0] + ((vb + 64 + lg * 16) ^ sw));
#pragma unroll
            for (int rs = 0; rs < 2; rs++) {
                o[rs][ns] = MFMA(v0, pf[rs][0], o[rs][ns]);
                o[rs][ns] = MFMA(v1, pf[rs][1], o[rs][ns]);
            }
        }
        if (t + 1 < 32) aon_nxt = write_tile(cur ^ 1);
    }
#pragma unroll
    for (int rs = 0; rs < 2; rs++) {
        float inv = 1.f / lacc[rs][0];
        int qg = qb0 + wave * 32 + rs * 16 + lr;
#pragma unroll
        for (int ns = 0; ns < 4; ns++) {
            u16x4 ov;
#pragma unroll
            for (int i = 0; i < 4; i++) ov[i] = f2bf(o[rs][ns][i] * inv);
            *(u16x4*)(outb + (size_t)(b * 2048 + qg) * 1024 + h * 64 + ns * 16 + lg * 4) = ov;
        }
    }
}

// ---------------- fused residual add + LayerNorm ----------------
template <bool WB>
__global__ __launch_bounds__(256) void k_add_ln(const float* __restrict__ y,
                                                const float* __restrict__ resid,
                                                float* __restrict__ outf,
                                                u16* __restrict__ outb,
                                                const float* __restrict__ alpha,
                                                const float* __restrict__ beta) {
    const int row = blockIdx.x, tid = threadIdx.x;
    const f32x4 a = ((const f32x4*)(y + (size_t)row * 1024))[tid];
    const f32x4 r = ((const f32x4*)(resid + (size_t)row * 1024))[tid];
    f32x4 t;
#pragma unroll
    for (int i = 0; i < 4; i++) t[i] = a[i] + r[i];
    float s = t[0] + t[1] + t[2] + t[3];
    float ss = t[0] * t[0] + t[1] * t[1] + t[2] * t[2] + t[3] * t[3];
#pragma unroll
    for (int m2 = 1; m2 < 64; m2 <<= 1) {
        s += __shfl_xor(s, m2);
        ss += __shfl_xor(ss, m2);
    }
    __shared__ float ps[4], pss[4];
    if ((tid & 63) == 0) { ps[tid >> 6] = s; pss[tid >> 6] = ss; }
    __syncthreads();
    s = ps[0] + ps[1] + ps[2] + ps[3];
    ss = pss[0] + pss[1] + pss[2] + pss[3];
    const float mean = s * (1.f / 1024.f);
    float var = (ss - 1024.f * mean * mean) * (1.f / 1023.f);
    var = fmaxf(var, 0.f);
    const float inv = alpha[0] / (sqrtf(var) + 1e-6f);
    const float bet = beta[0];
    f32x4 oo;
#pragma unroll
    for (int i = 0; i < 4; i++) oo[i] = (t[i] - mean) * inv + bet;
    ((f32x4*)(outf + (size_t)row * 1024))[tid] = oo;
    if constexpr (WB) {
        u16x4 ob;
#pragma unroll
        for (int i = 0; i < 4; i++) ob[i] = f2bf(oo[i]);
        ((u16x4*)(outb + (size_t)row * 1024))[tid] = ob;
    }
}

// ---------------- launch ----------------
extern "C" void kernel_launch(void* const* d_in, const int* in_sizes, int n_in,
                              void* d_out, int out_size, void* d_ws, size_t ws_size,
                              hipStream_t stream) {
    const float* x   = (const float*)d_in[0];
    const int*   msk = (const int*)d_in[1];
    const float* wq  = (const float*)d_in[2];
    const float* wk  = (const float*)d_in[3];
    const float* wv  = (const float*)d_in[4];
    const float* wo  = (const float*)d_in[5];
    const float* w1  = (const float*)d_in[6];
    const float* b1  = (const float*)d_in[7];
    const float* w2  = (const float*)d_in[8];
    const float* b2  = (const float*)d_in[9];
    const float* a1  = (const float*)d_in[10];
    const float* bt1 = (const float*)d_in[11];
    const float* a2  = (const float*)d_in[12];
    const float* bt2 = (const float*)d_in[13];
    float* out = (float*)d_out;

    char* ws = (char*)d_ws;
    size_t off = 0;
    auto alloc = [&](size_t bytes) {
        void* p = ws + off;
        off += (bytes + 255) & ~(size_t)255;
        return p;
    };
    u16* xb    = (u16*)alloc((size_t)M_ * D_ * 2);
    u16* wqkvT = (u16*)alloc((size_t)3 * D_ * D_ * 2);
    u16* woT   = (u16*)alloc((size_t)D_ * D_ * 2);
    u16* w1T   = (u16*)alloc((size_t)DFF_ * D_ * 2);
    u16* w2T   = (u16*)alloc((size_t)D_ * DFF_ * 2);
    u32* mbits = (u32*)alloc((size_t)B_ * S_ * 64 * 4);
    u16* aout  = (u16*)alloc((size_t)M_ * D_ * 2);
    float* y   = (float*)alloc((size_t)M_ * D_ * 4);
    float* x1  = (float*)alloc((size_t)M_ * D_ * 4);
    u16* x1b   = (u16*)alloc((size_t)M_ * D_ * 2);
    u16* vTb   = (u16*)alloc((size_t)64 * 64 * 2048 * 2);
    u16* qkv   = (u16*)alloc((size_t)M_ * DFF_ * 2);
    u16* hft   = qkv;

    // 1) pre-pass
    k_pack_mask<<<dim3((B_ * S_ * 64) / 256), 256, 0, stream>>>(msk, mbits, B_ * S_ * 64);
    k_cast_bf16<<<dim3((M_ * D_ / 4) / 256), 256, 0, stream>>>(x, xb, M_ * D_ / 4);
    dim3 tb(32, 8);
    k_transpose_cast<<<dim3(32, 32), tb, 0, stream>>>(wq, wqkvT, D_, D_);
    k_transpose_cast<<<dim3(32, 32), tb, 0, stream>>>(wk, wqkvT + D_ * D_, D_, D_);
    k_transpose_cast<<<dim3(32, 32), tb, 0, stream>>>(wv, wqkvT + 2 * D_ * D_, D_, D_);
    k_transpose_cast<<<dim3(32, 32), tb, 0, stream>>>(wo, woT, D_, D_);
    k_transpose_cast<<<dim3(128, 32), tb, 0, stream>>>(w1, w1T, D_, DFF_);
    k_transpose_cast<<<dim3(32, 128), tb, 0, stream>>>(w2, w2T, DFF_, D_);

    // 2) QKV projection: 256^2 tiles, grid 32x12=384
    k_gemm256<0><<<dim3(384), 512, 0, stream>>>(xb, wqkvT, nullptr, qkv, nullptr,
                                                3 * D_, D_);
    // 2b) V -> V^T
    k_transpose_v<<<dim3(32, 64), 256, 0, stream>>>(qkv, vTb);
    // 3) flash attention
    k_attn<<<dim3(16, 64), 256, 0, stream>>>(qkv, vTb, mbits, aout);
    // 4) output projection (128^2, grid 256)
    k_gemm8<1><<<dim3(512), 512, 0, stream>>>(aout, woT, y, nullptr, nullptr, D_, D_);
    // 5) LN1
    k_add_ln<true><<<dim3(M_), 256, 0, stream>>>(y, x, x1, x1b, a1, bt1);
    // 6) FFN1: 256^2 tiles, grid 32x16=512
    k_gemm256<2><<<dim3(512), 512, 0, stream>>>(x1b, w1T, nullptr, hft, b1, DFF_, D_);
    // 7) FFN2 (128^2, grid 512)
    k_gemm8<3><<<dim3(512), 512, 0, stream>>>(hft, w2T, y, nullptr, b2, D_, DFF_);
    // 8) LN2 -> d_out
    k_add_ln<false><<<dim3(M_), 256, 0, stream>>>(y, x1, out, nullptr, a2, bt2);
}

// Round 6
// 412.686 us; speedup vs baseline: 1.5622x; 1.0179x over previous
//
#include <hip/hip_runtime.h>
#include <stdint.h>

typedef __bf16 bf16x8 __attribute__((ext_vector_type(8)));
typedef float f32x4 __attribute__((ext_vector_type(4)));
typedef unsigned short u16;
typedef u16 u16x8 __attribute__((ext_vector_type(8)));
typedef u16 u16x4 __attribute__((ext_vector_type(4)));
typedef uint32_t u32;

#define DEV __device__ __forceinline__
#define MFMA(a, b, c) __builtin_amdgcn_mfma_f32_16x16x32_bf16(a, b, c, 0, 0, 0)

static constexpr int B_ = 4, S_ = 2048, M_ = 8192, D_ = 1024, H_ = 16, DFF_ = 4096;

DEV u16 f2bf(float f) {
    union { float f; u32 u; } c; c.f = f;
    u32 u = c.u;
    return (u16)((u + 0x7fffu + ((u >> 16) & 1u)) >> 16);
}

DEV u32 cvt_pk_bf16(float lo, float hi) {
    u32 r;
    asm("v_cvt_pk_bf16_f32 %0, %1, %2" : "=v"(r) : "v"(lo), "v"(hi));
    return r;
}

DEV float v_exp2(float x) {  // raw 2^x
    float r;
    asm("v_exp_f32 %0, %1" : "=v"(r) : "v"(x));
    return r;
}

DEV void gload16(void* lds, const void* g) {
    __builtin_amdgcn_global_load_lds(
        (const __attribute__((address_space(1))) unsigned int*)g,
        (__attribute__((address_space(3))) unsigned int*)lds, 16, 0, 0);
}

// ---------------- pre-pass kernels ----------------

__global__ __launch_bounds__(256) void k_pack_mask(const int* __restrict__ m,
                                                   u32* __restrict__ bits, int nwords) {
    int w = blockIdx.x * 256 + threadIdx.x;
    if (w >= nwords) return;
    const int4* s = (const int4*)(m + (size_t)w * 32);
    u32 r = 0;
#pragma unroll
    for (int j = 0; j < 8; j++) {
        int4 v = s[j];
        r |= (u32)(v.x != 0) << (j * 4) | (u32)(v.y != 0) << (j * 4 + 1) |
             (u32)(v.z != 0) << (j * 4 + 2) | (u32)(v.w != 0) << (j * 4 + 3);
    }
    bits[w] = r;
}

__global__ __launch_bounds__(256) void k_cast_bf16(const float* __restrict__ s,
                                                   u16* __restrict__ d, int n4) {
    int i = blockIdx.x * 256 + threadIdx.x;
    if (i >= n4) return;
    f32x4 v = ((const f32x4*)s)[i];
    u16x4 o;
    o[0] = f2bf(v[0]); o[1] = f2bf(v[1]); o[2] = f2bf(v[2]); o[3] = f2bf(v[3]);
    ((u16x4*)d)[i] = o;
}

// src [K][N] f32 -> dst [N][K] bf16
__global__ void k_transpose_cast(const float* __restrict__ s, u16* __restrict__ d,
                                 int K, int N) {
    __shared__ float t[32][33];
    int n0 = blockIdx.x * 32, k0 = blockIdx.y * 32;
    int tx = threadIdx.x, ty = threadIdx.y;
#pragma unroll
    for (int i = 0; i < 4; i++)
        t[ty + i * 8][tx] = s[(size_t)(k0 + ty + i * 8) * N + n0 + tx];
    __syncthreads();
#pragma unroll
    for (int i = 0; i < 4; i++)
        d[(size_t)(n0 + ty + i * 8) * K + k0 + tx] = f2bf(t[tx][ty + i * 8]);
}

// ---- 128x128 8-wave GEMM, BK=64, dbuf LDS, counted vmcnt, T2 swizzle ----
// EPI 0: QKV scatter (Q scaled by 0.125*log2e; V written transposed to Vt)
// EPI 1: f32 + resid; EPI 2: +bias relu bf16; EPI 3: +bias + resid f32
template <int EPI>
__global__ __launch_bounds__(512, 4) void k_gemm8(const u16* __restrict__ A,
                                                  const u16* __restrict__ Bt,
                                                  float* __restrict__ Cf,
                                                  u16* __restrict__ Cb,
                                                  const float* __restrict__ bias,
                                                  const float* __restrict__ resid,
                                                  u16* __restrict__ Vt,
                                                  int N, int K) {
    __shared__ u16 As[2][128 * 64];
    __shared__ u16 Bs[2][128 * 64];
    const int tid = threadIdx.x, lane = tid & 63, wave = tid >> 6;
    const int lr = lane & 15, lg = lane >> 4;
    const int wm = wave >> 1, wn = wave & 1;
    const int nbx = N >> 7;
    const int chunk = gridDim.x >> 3;
    const int id = ((int)blockIdx.x & 7) * chunk + ((int)blockIdx.x >> 3);
    const size_t row0 = (size_t)(id / nbx) * 128;
    const int col0 = (id % nbx) * 128;
    const int srow = lane >> 3;
    const int sgr = (lane & 7) ^ srow;
    const int NT = K >> 6;
    f32x4 acc[2][4] = {};

    auto stage = [&](int buf, int t) {
#pragma unroll
        for (int i = 0; i < 2; i++) {
            int c = i * 8 + wave;
            gload16((char*)&As[buf][0] + c * 1024,
                    (const char*)(A + (row0 + c * 8 + srow) * K + t * 64 + sgr * 8));
        }
#pragma unroll
        for (int i = 0; i < 2; i++) {
            int c = i * 8 + wave;
            gload16((char*)&Bs[buf][0] + c * 1024,
                    (const char*)(Bt + (size_t)(col0 + c * 8 + srow) * K + t * 64 + sgr * 8));
        }
    };

    stage(0, 0);
    for (int t = 0; t < NT; ++t) {
        const int cur = t & 1;
        if (t + 1 < NT) {
            stage(cur ^ 1, t + 1);
            asm volatile("s_waitcnt vmcnt(4)" ::: "memory");
        } else {
            asm volatile("s_waitcnt vmcnt(0)" ::: "memory");
        }
        __builtin_amdgcn_s_barrier();
        asm volatile("" ::: "memory");
        bf16x8 bF[4][2];
#pragma unroll
        for (int n = 0; n < 4; n++) {
            int r = wn * 64 + n * 16 + lr;
            int rb = r * 128, sw = (r & 7) << 4;
#pragma unroll
            for (int ks = 0; ks < 2; ks++)
                bF[n][ks] = *(const bf16x8*)((char*)&Bs[cur][0] +
                                             (rb + ((ks * 64 + lg * 16) ^ sw)));
        }
#pragma unroll
        for (int m = 0; m < 2; m++) {
            int r = wm * 32 + m * 16 + lr;
            int rb = r * 128, sw = (r & 7) << 4;
            bf16x8 a0 = *(const bf16x8*)((char*)&As[cur][0] + (rb + ((lg * 16) ^ sw)));
            bf16x8 a1 = *(const bf16x8*)((char*)&As[cur][0] + (rb + ((64 + lg * 16) ^ sw)));
            __builtin_amdgcn_s_setprio(1);
#pragma unroll
            for (int n = 0; n < 4; n++) {
                acc[m][n] = MFMA(a0, bF[n][0], acc[m][n]);
                acc[m][n] = MFMA(a1, bF[n][1], acc[m][n]);
            }
            __builtin_amdgcn_s_setprio(0);
        }
        asm volatile("" ::: "memory");
        __builtin_amdgcn_s_barrier();
    }
#pragma unroll
    for (int m = 0; m < 2; m++)
#pragma unroll
        for (int n = 0; n < 4; n++) {
            const int cg = col0 + wn * 64 + n * 16 + lr;
            const int rbase = (int)row0 + wm * 32 + m * 16 + lg * 4;
            if constexpr (EPI == 0) {
                const int proj = cg >> 10, hh = (cg >> 6) & 15, dk = cg & 63;
                const int b = rbase >> 11, s = rbase & 2047;
                if (proj == 2) {  // V: write transposed, vT[b*16+hh][dk][s..s+3]
                    u16x4 ov;
#pragma unroll
                    for (int i = 0; i < 4; i++) ov[i] = f2bf(acc[m][n][i]);
                    *(u16x4*)(Vt + ((size_t)(b * 16 + hh) * 64 + dk) * 2048 + s) = ov;
                } else {
                    const float sc = (proj == 0) ? 0.1803368801111832f : 1.f;
                    size_t base = ((size_t)(proj * 64 + b * 16 + hh) * 2048 + s) * 64 + dk;
#pragma unroll
                    for (int i = 0; i < 4; i++)
                        Cb[base + (size_t)i * 64] = f2bf(acc[m][n][i] * sc);
                }
            } else {
#pragma unroll
                for (int i = 0; i < 4; i++) {
                    const int rg = rbase + i;
                    float v = acc[m][n][i];
                    if constexpr (EPI == 1) {
                        Cf[(size_t)rg * N + cg] = v + resid[(size_t)rg * N + cg];
                    } else if constexpr (EPI == 2) {
                        v += bias[cg];
                        v = v > 0.f ? v : 0.f;
                        Cb[(size_t)rg * N + cg] = f2bf(v);
                    } else {
                        Cf[(size_t)rg * N + cg] = v + bias[cg] + resid[(size_t)rg * N + cg];
                    }
                }
            }
        }
}

// ---- 256x256 8-wave 4-phase GEMM (FFN1), BK=64, dbuf LDS, counted vmcnt ----
template <int EPI>
__global__ __launch_bounds__(512, 2) void k_gemm256(const u16* __restrict__ A,
                                                    const u16* __restrict__ Bt,
                                                    float* __restrict__ Cf,
                                                    u16* __restrict__ Cb,
                                                    const float* __restrict__ bias,
                                                    int N, int K) {
    __shared__ u16 As[2][256 * 64];
    __shared__ u16 Bs[2][256 * 64];
    const int tid = threadIdx.x, lane = tid & 63, wave = tid >> 6;
    const int lr = lane & 15, lg = lane >> 4;
    const int wm = wave >> 2, wn = wave & 3;
    const int nbx = N >> 8;
    const int chunk = gridDim.x >> 3;
    const int id = ((int)blockIdx.x & 7) * chunk + ((int)blockIdx.x >> 3);
    const size_t row0 = (size_t)(id / nbx) * 256;
    const int col0 = (id % nbx) * 256;
    const int srow = lane >> 3;
    const int sgr = (lane & 7) ^ srow;
    const int NT = K >> 6;
    f32x4 acc[8][4] = {};

    auto stage_half = [&](int isB, int buf, int t, int h) {
        const u16* g = isB ? Bt : A;
        const size_t grow0 = isB ? (size_t)col0 : row0;
        char* base = isB ? (char*)&Bs[buf][0] : (char*)&As[buf][0];
#pragma unroll
        for (int l = 0; l < 2; l++) {
            int rt = h * 128 + l * 64 + wave * 8;
            gload16(base + rt * 128,
                    (const char*)(g + (grow0 + rt + srow) * K + t * 64 + sgr * 8));
        }
    };
    auto rdA = [&](int cur, int mh, int m, int kk) -> bf16x8 {
        int r = wm * 128 + mh * 64 + m * 16 + lr;
        int gi = kk * 4 + lg;
        return *(const bf16x8*)((char*)&As[cur][0] + r * 128 + ((gi ^ (r & 7)) << 4));
    };
    auto rdB = [&](int cur, int nh, int n, int kk) -> bf16x8 {
        int r = wn * 64 + nh * 32 + n * 16 + lr;
        int gi = kk * 4 + lg;
        return *(const bf16x8*)((char*)&Bs[cur][0] + r * 128 + ((gi ^ (r & 7)) << 4));
    };

    stage_half(0, 0, 0, 0); stage_half(0, 0, 0, 1);
    stage_half(1, 0, 0, 0); stage_half(1, 0, 0, 1);
    stage_half(1, 1, 1, 0); stage_half(1, 1, 1, 1);
    asm volatile("s_waitcnt vmcnt(4)" ::: "memory");
    __builtin_amdgcn_s_barrier();

    bf16x8 aF[4][2], b0F[2][2], b1F[2][2];
    for (int t = 0; t < NT; ++t) {
        const int cur = t & 1, nxt = cur ^ 1;
        // ---- P0 ----
#pragma unroll
        for (int m = 0; m < 4; m++) { aF[m][0] = rdA(cur, 0, m, 0); aF[m][1] = rdA(cur, 0, m, 1); }
#pragma unroll
        for (int n = 0; n < 2; n++) { b0F[n][0] = rdB(cur, 0, n, 0); b0F[n][1] = rdB(cur, 0, n, 1); }
        if (t + 1 < NT) stage_half(0, nxt, t + 1, 0);
        __builtin_amdgcn_s_barrier();
        asm volatile("s_waitcnt lgkmcnt(0)" ::: "memory");
        __builtin_amdgcn_sched_barrier(0);
        __builtin_amdgcn_s_setprio(1);
#pragma unroll
        for (int m = 0; m < 4; m++)
#pragma unroll
            for (int n = 0; n < 2; n++) {
                acc[m][n] = MFMA(aF[m][0], b0F[n][0], acc[m][n]);
                acc[m][n] = MFMA(aF[m][1], b0F[n][1], acc[m][n]);
            }
        __builtin_amdgcn_s_setprio(0);
        __builtin_amdgcn_s_barrier();
        // ---- P1 ----
#pragma unroll
        for (int n = 0; n < 2; n++) { b1F[n][0] = rdB(cur, 1, n, 0); b1F[n][1] = rdB(cur, 1, n, 1); }
        if (t + 1 < NT) stage_half(0, nxt, t + 1, 1);
        __builtin_amdgcn_s_barrier();
        asm volatile("s_waitcnt lgkmcnt(0)" ::: "memory");
        __builtin_amdgcn_sched_barrier(0);
        __builtin_amdgcn_s_setprio(1);
#pragma unroll
        for (int m = 0; m < 4; m++)
#pragma unroll
            for (int n = 0; n < 2; n++) {
                acc[m][2 + n] = MFMA(aF[m][0], b1F[n][0], acc[m][2 + n]);
                acc[m][2 + n] = MFMA(aF[m][1], b1F[n][1], acc[m][2 + n]);
            }
        __builtin_amdgcn_s_setprio(0);
        __builtin_amdgcn_s_barrier();
        // ---- P2 ----
#pragma unroll
        for (int m = 0; m < 4; m++) { aF[m][0] = rdA(cur, 1, m, 0); aF[m][1] = rdA(cur, 1, m, 1); }
        if (t + 2 < NT) stage_half(1, cur, t + 2, 0);
        __builtin_amdgcn_s_barrier();
        asm volatile("s_waitcnt lgkmcnt(0)" ::: "memory");
        __builtin_amdgcn_sched_barrier(0);
        __builtin_amdgcn_s_setprio(1);
#pragma unroll
        for (int m = 0; m < 4; m++)
#pragma unroll
            for (int n = 0; n < 2; n++) {
                acc[4 + m][2 + n] = MFMA(aF[m][0], b1F[n][0], acc[4 + m][2 + n]);
                acc[4 + m][2 + n] = MFMA(aF[m][1], b1F[n][1], acc[4 + m][2 + n]);
            }
        __builtin_amdgcn_s_setprio(0);
        __builtin_amdgcn_s_barrier();
        // ---- P3 ----
        if (t + 2 < NT) stage_half(1, cur, t + 2, 1);
        if (t + 1 < NT) {
            if (t + 2 < NT) asm volatile("s_waitcnt vmcnt(4)" ::: "memory");
            else            asm volatile("s_waitcnt vmcnt(0)" ::: "memory");
        }
        __builtin_amdgcn_s_barrier();
        __builtin_amdgcn_s_setprio(1);
#pragma unroll
        for (int m = 0; m < 4; m++)
#pragma unroll
            for (int n = 0; n < 2; n++) {
                acc[4 + m][n] = MFMA(aF[m][0], b0F[n][0], acc[4 + m][n]);
                acc[4 + m][n] = MFMA(aF[m][1], b0F[n][1], acc[4 + m][n]);
            }
        __builtin_amdgcn_s_setprio(0);
        __builtin_amdgcn_s_barrier();
    }
#pragma unroll
    for (int m = 0; m < 8; m++)
#pragma unroll
        for (int n = 0; n < 4; n++)
#pragma unroll
            for (int i = 0; i < 4; i++) {
                int rg = (int)row0 + wm * 128 + m * 16 + lg * 4 + i;
                int cg = col0 + wn * 64 + n * 16 + lr;
                float v = acc[m][n][i];
                if constexpr (EPI == 2) {
                    v += bias[cg];
                    v = v > 0.f ? v : 0.f;
                    Cb[(size_t)rg * N + cg] = f2bf(v);
                } else {
                    Cf[(size_t)rg * N + cg] = v;
                }
            }
}

// ------- flash attention: fixed-offset softmax + async-stage dbuf -------
__global__ __launch_bounds__(256) void k_attn(const u16* __restrict__ qkv,
                                              const u16* __restrict__ vT,
                                              const u32* __restrict__ mbits,
                                              u16* __restrict__ outb) {
    __shared__ u16 Kt[2][64 * 64];
    __shared__ u16 Vt[2][64 * 64];
    __shared__ u16 Pt[4][32 * 64];
    __shared__ u32 pm[2][128][2];
    const int tid = threadIdx.x, lane = tid & 63, wave = tid >> 6;
    const int lr = lane & 15, lg = lane >> 4;
    const int id0 = blockIdx.y * 16 + blockIdx.x;
    const int id = (id0 & 7) * 128 + (id0 >> 3);
    const int bh = id >> 4;
    const int b = bh >> 4, h = bh & 15;
    const int qb0 = (id & 15) * 128;
    const size_t qbase = (size_t)bh * (2048 * 64);
    const size_t kbase = (size_t)(64 + bh) * (2048 * 64);
    const size_t vtbase = (size_t)bh * (64 * 2048);

    bf16x8 qf[2][2];
    const int q0 = qb0 + wave * 32;
#pragma unroll
    for (int rs = 0; rs < 2; rs++)
#pragma unroll
        for (int kf = 0; kf < 2; kf++)
            qf[rs][kf] = *(const bf16x8*)(qkv + qbase +
                                          (size_t)(q0 + rs * 16 + lr) * 64 + kf * 32 + lg * 8);

    u16x8 ones_u;
#pragma unroll
    for (int e = 0; e < 8; e++) ones_u[e] = 0x3f80;
    const bf16x8 ones8 = *(const bf16x8*)&ones_u;

    f32x4 o[2][4] = {};
    f32x4 lacc[2] = {};
    const int str = tid >> 2, sq = tid & 3;
    const int swzs = (str & 7) << 4;
    const f32x4 zinit = {-16.f, -16.f, -16.f, -16.f};

    u16x8 krA, krB, vrA, vrB; u32 mwA;
    auto issue_loads = [&](int kv0n) {
        const u16* ksrc = qkv + kbase + (size_t)(kv0n + str) * 64 + sq * 16;
        krA = *(const u16x8*)ksrc; krB = *(const u16x8*)(ksrc + 8);
        const u16* vsrc = vT + vtbase + (size_t)str * 2048 + kv0n + sq * 16;
        vrA = *(const u16x8*)vsrc; vrB = *(const u16x8*)(vsrc + 8);
        mwA = mbits[(size_t)(b * 2048 + qb0 + (tid >> 1)) * 64 + (kv0n >> 5) + (tid & 1)];
    };
    auto write_tile = [&](int buf) -> bool {
        int b0 = str * 128 + sq * 32;
        *(u16x8*)((char*)&Kt[buf][0] + ((b0) ^ swzs)) = krA;
        *(u16x8*)((char*)&Kt[buf][0] + ((b0 + 16) ^ swzs)) = krB;
        *(u16x8*)((char*)&Vt[buf][0] + ((b0) ^ swzs)) = vrA;
        *(u16x8*)((char*)&Vt[buf][0] + ((b0 + 16) ^ swzs)) = vrB;
        pm[buf][tid >> 1][tid & 1] = mwA;
        return (__ballot(mwA == 0xffffffffu) == ~0ull);
    };

    issue_loads(0);
    bool aon_nxt = write_tile(0);
    for (int t = 0; t < 32; ++t) {
        const int cur = t & 1;
        const bool aon_cur = aon_nxt;
        if (t + 1 < 32) issue_loads((t + 1) * 64);
        asm volatile("s_waitcnt lgkmcnt(0)" ::: "memory");
        __builtin_amdgcn_s_barrier();

        f32x4 st[2][4];
#pragma unroll
        for (int ks = 0; ks < 4; ks++) {
            int rr = ks * 16 + lr;
            int rb = rr * 128, sw = (rr & 7) << 4;
            bf16x8 k0 = *(const bf16x8*)((char*)&Kt[cur][0] + ((rb + lg * 16) ^ sw));
            bf16x8 k1 = *(const bf16x8*)((char*)&Kt[cur][0] + ((rb + 64 + lg * 16) ^ sw));
#pragma unroll
            for (int rs = 0; rs < 2; rs++) {
                f32x4 z = MFMA(k0, qf[rs][0], zinit);
                z = MFMA(k1, qf[rs][1], z);
                st[rs][ks] = z;
            }
        }
        if (!aon_cur) {
#pragma unroll
            for (int rs = 0; rs < 2; rs++) {
                u32 w0 = pm[cur][wave * 32 + rs * 16 + lr][0];
                u32 w1 = pm[cur][wave * 32 + rs * 16 + lr][1];
#pragma unroll
                for (int ks = 0; ks < 4; ks++)
#pragma unroll
                    for (int i = 0; i < 4; i++) {
                        int kv = ks * 16 + lg * 4 + i;
                        u32 w = (kv & 32) ? w1 : w0;
                        if (!((w >> (kv & 31)) & 1u)) st[rs][ks][i] = -1e9f;
                    }
            }
        }
#pragma unroll
        for (int rs = 0; rs < 2; rs++) {
            int prow = rs * 16 + lr;
            int pb = prow * 128, swp = (prow & 7) << 4;
#pragma unroll
            for (int ks = 0; ks < 4; ks++) {
                uint2 w;
                w.x = cvt_pk_bf16(v_exp2(st[rs][ks][0]), v_exp2(st[rs][ks][1]));
                w.y = cvt_pk_bf16(v_exp2(st[rs][ks][2]), v_exp2(st[rs][ks][3]));
                *(uint2*)((char*)&Pt[wave][0] + ((pb + ks * 32 + lg * 8) ^ swp)) = w;
            }
        }
        asm volatile("s_waitcnt lgkmcnt(0)" ::: "memory");
        __builtin_amdgcn_sched_barrier(0);
        bf16x8 pf[2][2];
#pragma unroll
        for (int rs = 0; rs < 2; rs++) {
            int prow = rs * 16 + lr;
            int pb = prow * 128, swp = (prow & 7) << 4;
            pf[rs][0] = *(const bf16x8*)((char*)&Pt[wave][0] + ((pb + lg * 16) ^ swp));
            pf[rs][1] = *(const bf16x8*)((char*)&Pt[wave][0] + ((pb + 64 + lg * 16) ^ swp));
        }
#pragma unroll
        for (int rs = 0; rs < 2; rs++) {
            lacc[rs] = MFMA(ones8, pf[rs][0], lacc[rs]);
            lacc[rs] = MFMA(ones8, pf[rs][1], lacc[rs]);
        }
#pragma unroll
        for (int ns = 0; ns < 4; ns++) {
            int vr = ns * 16 + lr;
            int vb = vr * 128, sw = (vr & 7) << 4;
            bf16x8 v0 = *(const bf16x8*)((char*)&Vt[cur][0] + ((vb + lg * 16) ^ sw));
            bf16x8 v1 = *(const bf16x8*)((char*)&Vt[cur][0] + ((vb + 64 + lg * 16) ^ sw));
#pragma unroll
            for (int rs = 0; rs < 2; rs++) {
                o[rs][ns] = MFMA(v0, pf[rs][0], o[rs][ns]);
                o[rs][ns] = MFMA(v1, pf[rs][1], o[rs][ns]);
            }
        }
        if (t + 1 < 32) aon_nxt = write_tile(cur ^ 1);
    }
#pragma unroll
    for (int rs = 0; rs < 2; rs++) {
        float inv = 1.f / lacc[rs][0];
        int qg = qb0 + wave * 32 + rs * 16 + lr;
#pragma unroll
        for (int ns = 0; ns < 4; ns++) {
            u16x4 ov;
#pragma unroll
            for (int i = 0; i < 4; i++) ov[i] = f2bf(o[rs][ns][i] * inv);
            *(u16x4*)(outb + (size_t)(b * 2048 + qg) * 1024 + h * 64 + ns * 16 + lg * 4) = ov;
        }
    }
}

// ------- fused LayerNorm (input already has residual added) -------
template <bool WB>
__global__ __launch_bounds__(256) void k_ln(const float* __restrict__ tin,
                                            float* __restrict__ outf,
                                            u16* __restrict__ outb,
                                            const float* __restrict__ alpha,
                                            const float* __restrict__ beta) {
    const int row = blockIdx.x, tid = threadIdx.x;
    const f32x4 t = ((const f32x4*)(tin + (size_t)row * 1024))[tid];
    float s = t[0] + t[1] + t[2] + t[3];
    float ss = t[0] * t[0] + t[1] * t[1] + t[2] * t[2] + t[3] * t[3];
#pragma unroll
    for (int m2 = 1; m2 < 64; m2 <<= 1) {
        s += __shfl_xor(s, m2);
        ss += __shfl_xor(ss, m2);
    }
    __shared__ float ps[4], pss[4];
    if ((tid & 63) == 0) { ps[tid >> 6] = s; pss[tid >> 6] = ss; }
    __syncthreads();
    s = ps[0] + ps[1] + ps[2] + ps[3];
    ss = pss[0] + pss[1] + pss[2] + pss[3];
    const float mean = s * (1.f / 1024.f);
    float var = (ss - 1024.f * mean * mean) * (1.f / 1023.f);
    var = fmaxf(var, 0.f);
    const float inv = alpha[0] / (sqrtf(var) + 1e-6f);
    const float bet = beta[0];
    f32x4 oo;
#pragma unroll
    for (int i = 0; i < 4; i++) oo[i] = (t[i] - mean) * inv + bet;
    ((f32x4*)(outf + (size_t)row * 1024))[tid] = oo;
    if constexpr (WB) {
        u16x4 ob;
#pragma unroll
        for (int i = 0; i < 4; i++) ob[i] = f2bf(oo[i]);
        ((u16x4*)(outb + (size_t)row * 1024))[tid] = ob;
    }
}

// ---------------- launch ----------------
extern "C" void kernel_launch(void* const* d_in, const int* in_sizes, int n_in,
                              void* d_out, int out_size, void* d_ws, size_t ws_size,
                              hipStream_t stream) {
    const float* x   = (const float*)d_in[0];
    const int*   msk = (const int*)d_in[1];
    const float* wq  = (const float*)d_in[2];
    const float* wk  = (const float*)d_in[3];
    const float* wv  = (const float*)d_in[4];
    const float* wo  = (const float*)d_in[5];
    const float* w1  = (const float*)d_in[6];
    const float* b1  = (const float*)d_in[7];
    const float* w2  = (const float*)d_in[8];
    const float* b2  = (const float*)d_in[9];
    const float* a1  = (const float*)d_in[10];
    const float* bt1 = (const float*)d_in[11];
    const float* a2  = (const float*)d_in[12];
    const float* bt2 = (const float*)d_in[13];
    float* out = (float*)d_out;

    char* ws = (char*)d_ws;
    size_t off = 0;
    auto alloc = [&](size_t bytes) {
        void* p = ws + off;
        off += (bytes + 255) & ~(size_t)255;
        return p;
    };
    u16* xb    = (u16*)alloc((size_t)M_ * D_ * 2);
    u16* wqkvT = (u16*)alloc((size_t)3 * D_ * D_ * 2);
    u16* woT   = (u16*)alloc((size_t)D_ * D_ * 2);
    u16* w1T   = (u16*)alloc((size_t)DFF_ * D_ * 2);
    u16* w2T   = (u16*)alloc((size_t)D_ * DFF_ * 2);
    u32* mbits = (u32*)alloc((size_t)B_ * S_ * 64 * 4);
    u16* aout  = (u16*)alloc((size_t)M_ * D_ * 2);
    float* y   = (float*)alloc((size_t)M_ * D_ * 4);
    float* x1  = (float*)alloc((size_t)M_ * D_ * 4);
    u16* x1b   = (u16*)alloc((size_t)M_ * D_ * 2);
    u16* vTb   = (u16*)alloc((size_t)64 * 64 * 2048 * 2);
    u16* qkv   = (u16*)alloc((size_t)M_ * DFF_ * 2);
    u16* hft   = qkv;

    // 1) pre-pass
    k_pack_mask<<<dim3((B_ * S_ * 64) / 256), 256, 0, stream>>>(msk, mbits, B_ * S_ * 64);
    k_cast_bf16<<<dim3((M_ * D_ / 4) / 256), 256, 0, stream>>>(x, xb, M_ * D_ / 4);
    dim3 tb(32, 8);
    k_transpose_cast<<<dim3(32, 32), tb, 0, stream>>>(wq, wqkvT, D_, D_);
    k_transpose_cast<<<dim3(32, 32), tb, 0, stream>>>(wk, wqkvT + D_ * D_, D_, D_);
    k_transpose_cast<<<dim3(32, 32), tb, 0, stream>>>(wv, wqkvT + 2 * D_ * D_, D_, D_);
    k_transpose_cast<<<dim3(32, 32), tb, 0, stream>>>(wo, woT, D_, D_);
    k_transpose_cast<<<dim3(128, 32), tb, 0, stream>>>(w1, w1T, D_, DFF_);
    k_transpose_cast<<<dim3(32, 128), tb, 0, stream>>>(w2, w2T, DFF_, D_);

    // 2) QKV projection (128^2, 1536 blocks = 3 exact co-resident rounds);
    //    V written directly transposed into vTb by the epilogue.
    k_gemm8<0><<<dim3(1536), 512, 0, stream>>>(xb, wqkvT, nullptr, qkv, nullptr,
                                               nullptr, vTb, 3 * D_, D_);
    // 3) flash attention
    k_attn<<<dim3(16, 64), 256, 0, stream>>>(qkv, vTb, mbits, aout);
    // 4) output projection + residual: y = aout@woT + x
    k_gemm8<1><<<dim3(512), 512, 0, stream>>>(aout, woT, y, nullptr, nullptr, x,
                                              nullptr, D_, D_);
    // 5) LN1 (single input)
    k_ln<true><<<dim3(M_), 256, 0, stream>>>(y, x1, x1b, a1, bt1);
    // 6) FFN1 (256^2 4-phase, 512 blocks = 2 exact rounds)
    k_gemm256<2><<<dim3(512), 512, 0, stream>>>(x1b, w1T, nullptr, hft, b1, DFF_, D_);
    // 7) FFN2 + bias + residual: y = hft@w2T + b2 + x1
    k_gemm8<3><<<dim3(512), 512, 0, stream>>>(hft, w2T, y, nullptr, b2, x1,
                                              nullptr, D_, DFF_);
    // 8) LN2 -> d_out
    k_ln<false><<<dim3(M_), 256, 0, stream>>>(y, out, nullptr, a2, bt2);
}